// Round 4
// baseline (141.361 us; speedup 1.0000x reference)
//
#include <hip/hip_runtime.h>
#include <hip/hip_bf16.h>
#include <stdint.h>

using f32x4  = __attribute__((ext_vector_type(4))) float;
using bf16x8 = __attribute__((ext_vector_type(8))) short;

#define DEVINL static __device__ __forceinline__

DEVINL short f2bf(float f) {
    union { float f; uint32_t u; } v; v.f = f;
    uint32_t r = (v.u + 0x7FFFu + ((v.u >> 16) & 1u)) >> 16;   // RNE
    return (short)(uint16_t)r;
}
DEVINL float bf2f(short s) {
    union { uint32_t u; float f; } v; v.u = ((uint32_t)(uint16_t)s) << 16;
    return v.f;
}

// async global -> LDS, 16B per lane. LDS dest must be wave-uniform base (+lane*16 by HW).
DEVINL void gld16(const short* g, short* l) {
    __builtin_amdgcn_global_load_lds(
        (const __attribute__((address_space(1))) unsigned int*)g,
        (__attribute__((address_space(3))) unsigned int*)l, 16, 0, 0);
}

// ---------------- K0: weight prep (fp32 -> bf16, stack Wg|Wt|Wp) ----------------
__global__ __launch_bounds__(256) void k0_prep(
        const float* __restrict__ Wg, const float* __restrict__ Wt, const float* __restrict__ Wp,
        const float* __restrict__ bg, const float* __restrict__ bt, const float* __restrict__ bp,
        const float* __restrict__ Ww,
        short* __restrict__ W_all, short* __restrict__ Ww16, float* __restrict__ b_all) {
    int i = blockIdx.x * 256 + threadIdx.x;
    if (i < 384 * 256) {
        int r = i >> 8, c = i & 255;
        float v = (r < 128) ? Wg[r * 256 + c] : (r < 256) ? Wt[(r - 128) * 256 + c] : Wp[(r - 256) * 256 + c];
        W_all[i] = f2bf(v);
    } else if (i < 384 * 256 + 256 * 128) {
        int j = i - 384 * 256;
        Ww16[j] = f2bf(Ww[j]);
    }
    if (i < 384) {
        b_all[i] = (i < 128) ? bg[i] : (i < 256) ? bt[i - 128] : bp[i - 256];
    }
}

// ---------------- K1: fused conv1x1 x3 GEMM ----------------
// Out[b][n][o] (o in [0,384): 0..127=g, 128..255=theta, 256..383=phi), bf16
__global__ __launch_bounds__(256) void k1_conv(const float* __restrict__ x,
        const short* __restrict__ W_all, const float* __restrict__ b_all,
        short* __restrict__ Out) {
    __shared__ short xs[128 * 40];          // [n(128)][c(32)+pad8]
    const int ntile = blockIdx.x;           // 32
    const int otile = blockIdx.y;           // 3
    const int b     = blockIdx.z;           // 8
    const int tid  = threadIdx.x;
    const int lane = tid & 63;
    const int wave = tid >> 6;
    const int wn = wave >> 1, wo = wave & 1;
    const int l15 = lane & 15, lh = lane >> 4;

    f32x4 acc[4][4];
    #pragma unroll
    for (int i = 0; i < 4; i++)
        #pragma unroll
        for (int j = 0; j < 4; j++) acc[i][j] = f32x4{0.f, 0.f, 0.f, 0.f};

    const int n0 = ntile * 128;
    const int ob = otile * 128 + wo * 64;
    const float* xb = x + (size_t)b * 256 * 4096;

    for (int kt = 0; kt < 8; kt++) {
        __syncthreads();
        #pragma unroll
        for (int p = 0; p < 4; p++) {
            int c  = p * 8 + (tid >> 5);
            int n4 = (tid & 31) * 4;
            const float4 v = *(const float4*)(xb + (size_t)(kt * 32 + c) * 4096 + n0 + n4);
            xs[(n4 + 0) * 40 + c] = f2bf(v.x);
            xs[(n4 + 1) * 40 + c] = f2bf(v.y);
            xs[(n4 + 2) * 40 + c] = f2bf(v.z);
            xs[(n4 + 3) * 40 + c] = f2bf(v.w);
        }
        __syncthreads();

        bf16x8 a[4], w[4];
        #pragma unroll
        for (int nf = 0; nf < 4; nf++)
            a[nf] = *(const bf16x8*)&xs[(wn * 64 + nf * 16 + l15) * 40 + lh * 8];
        #pragma unroll
        for (int of = 0; of < 4; of++)
            w[of] = *(const bf16x8*)(W_all + (size_t)(ob + of * 16 + l15) * 256 + kt * 32 + lh * 8);
        #pragma unroll
        for (int nf = 0; nf < 4; nf++)
            #pragma unroll
            for (int of = 0; of < 4; of++)
                acc[nf][of] = __builtin_amdgcn_mfma_f32_16x16x32_bf16(a[nf], w[of], acc[nf][of], 0, 0, 0);
    }

    #pragma unroll
    for (int of = 0; of < 4; of++) {
        int o = ob + of * 16 + l15;
        float bias = b_all[o];
        #pragma unroll
        for (int nf = 0; nf < 4; nf++)
            #pragma unroll
            for (int r = 0; r < 4; r++) {
                int n = n0 + wn * 64 + nf * 16 + lh * 4 + r;
                Out[((size_t)b * 4096 + n) * 384 + o] = f2bf(acc[nf][of][r] + bias);
            }
    }
}

// ---------------- K2a: maxpool phi -> Kmat[b][m][c] (bf16) ----------------
__global__ __launch_bounds__(256) void k2a_poolK(const short* __restrict__ Out, short* __restrict__ Kmat) {
    int t = blockIdx.x * 256 + threadIdx.x;
    int c8 = t & 15;
    int m  = (t >> 4) & 1023;
    int b  = t >> 14;
    int hp = m >> 5, wp = m & 31;
    int n0 = hp * 128 + wp * 2;
    const short* base = Out + (size_t)b * 4096 * 384 + 256 + c8 * 8;
    bf16x8 v0 = *(const bf16x8*)(base + (size_t)(n0) * 384);
    bf16x8 v1 = *(const bf16x8*)(base + (size_t)(n0 + 1) * 384);
    bf16x8 v2 = *(const bf16x8*)(base + (size_t)(n0 + 64) * 384);
    bf16x8 v3 = *(const bf16x8*)(base + (size_t)(n0 + 65) * 384);
    bf16x8 vo;
    #pragma unroll
    for (int i = 0; i < 8; i++) {
        float mx = fmaxf(fmaxf(bf2f(v0[i]), bf2f(v1[i])), fmaxf(bf2f(v2[i]), bf2f(v3[i])));
        vo[i] = f2bf(mx);
    }
    *(bf16x8*)(Kmat + ((size_t)b * 1024 + m) * 128 + c8 * 8) = vo;
}

// ---------------- K2b: maxpool g -> Vmat[b][c][m] (bf16, transposed) ----------------
__global__ __launch_bounds__(256) void k2b_poolV(const short* __restrict__ Out, short* __restrict__ Vmat) {
    __shared__ short g[128 * 136];
    int b  = blockIdx.x >> 5;
    int hp = blockIdx.x & 31;
    int tid = threadIdx.x;
    {
        int nloc = tid >> 1;
        int ch0  = (tid & 1) * 8;
        const short* src = Out + ((size_t)b * 4096 + hp * 128 + nloc) * 384;
        #pragma unroll
        for (int i = 0; i < 8; i++) {
            int chunk = ch0 + i;
            *(bf16x8*)&g[nloc * 136 + chunk * 8] = *(const bf16x8*)(src + chunk * 8);
        }
    }
    __syncthreads();
    int wp = tid & 31;
    int cb = tid >> 5;
    #pragma unroll
    for (int pass = 0; pass < 16; pass++) {
        int c = pass * 8 + cb;
        float a0 = bf2f(g[(2 * wp) * 136 + c]);
        float a1 = bf2f(g[(2 * wp + 1) * 136 + c]);
        float a2 = bf2f(g[(64 + 2 * wp) * 136 + c]);
        float a3 = bf2f(g[(65 + 2 * wp) * 136 + c]);
        float mx = fmaxf(fmaxf(a0, a1), fmaxf(a2, a3));
        Vmat[((size_t)b * 128 + c) * 1024 + hp * 32 + wp] = f2bf(mx);
    }
}

// ---------------- K3: flash attention v4 ----------------
// 8 waves x 16 q-rows (128 rows/block), m-tile 64, dbuf global_load_lds staging,
// 2 blocks/CU -> 4 waves/SIMD. Defer-max online softmax. setprio around MFMA.
__global__ __launch_bounds__(512, 4) void k3_attn(const short* __restrict__ Out,
        const short* __restrict__ Kmat, const short* __restrict__ Vmat,
        short* __restrict__ Ybuf) {
    __shared__ short sK[2][64 * 128];   // [m][c], content chunk-XOR-swizzled by row
    __shared__ short sV[2][128 * 64];   // [c][m], content chunk-XOR-swizzled by row
    __shared__ short sP[8][16 * 64];    // per-wave P

    const int bid = blockIdx.x;         // 256
    const int b   = bid & 7;            // XCD swizzle: same-batch blocks share an XCD L2
    const int nt  = bid >> 3;           // 32 tiles of 128 rows
    const int tid = threadIdx.x;
    const int lane = tid & 63;
    const int wave = tid >> 6;          // 0..7
    const int l15 = lane & 15, lh = lane >> 4;
    const int n0 = nt * 128 + wave * 16;

    const short* Kb = Kmat + (size_t)b * 1024 * 128;
    const short* Vb = Vmat + (size_t)b * 128 * 1024;
    short* sPw = sP[wave];

    // stage one 64-wide m-tile (K: 64x128, V: 128x64) into buffer bufi
    // 16 wave-segments each for K and V, 2 per wave
    auto STAGE = [&](int t, int bufi) {
        const int m0 = t * 64;
        #pragma unroll
        for (int i = 0; i < 2; i++) {
            const int segb = (i * 8 + wave) * 64;          // wave-uniform segment base (chunks)
            const int rowK = (segb >> 4) + (lane >> 4);
            const int chkK = lane & 15;
            gld16(Kb + (size_t)(m0 + rowK) * 128 + ((chkK ^ (rowK & 15)) << 3),
                  &sK[bufi][segb * 8]);
            const int rowV = (segb >> 3) + (lane >> 3);
            const int chkV = lane & 7;
            gld16(Vb + (size_t)rowV * 1024 + m0 + ((chkV ^ (rowV & 7)) << 3),
                  &sV[bufi][segb * 8]);
        }
    };

    bf16x8 q[4];
    {
        const short* qrow = Out + ((size_t)b * 4096 + n0 + l15) * 384 + 128;
        #pragma unroll
        for (int ks = 0; ks < 4; ks++)
            q[ks] = *(const bf16x8*)(qrow + ks * 32 + lh * 8);
    }

    f32x4 y[8];
    #pragma unroll
    for (int cf = 0; cf < 8; cf++) y[cf] = f32x4{0.f, 0.f, 0.f, 0.f};
    float mrun[4], lrun[4];
    #pragma unroll
    for (int r = 0; r < 4; r++) { mrun[r] = -1e30f; lrun[r] = 0.f; }

    STAGE(0, 0);
    __syncthreads();
    int cur = 0;

    for (int t = 0; t < 16; t++) {
        if (t < 15) STAGE(t + 1, cur ^ 1);

        const short* cK = sK[cur];
        const short* cV = sV[cur];

        // S = Q K^T over 64-wide m tile
        f32x4 S[4];
        #pragma unroll
        for (int mf = 0; mf < 4; mf++) S[mf] = f32x4{0.f, 0.f, 0.f, 0.f};
        #pragma unroll
        for (int ks = 0; ks < 4; ks++) {
            bf16x8 kf[4];
            #pragma unroll
            for (int mf = 0; mf < 4; mf++) {
                int mrow = mf * 16 + l15;
                int jj   = ks * 4 + lh;
                kf[mf] = *(const bf16x8*)&cK[mrow * 128 + ((jj ^ (mrow & 15)) << 3)];
            }
            __builtin_amdgcn_s_setprio(1);
            #pragma unroll
            for (int mf = 0; mf < 4; mf++)
                S[mf] = __builtin_amdgcn_mfma_f32_16x16x32_bf16(q[ks], kf[mf], S[mf], 0, 0, 0);
            __builtin_amdgcn_s_setprio(0);
        }

        // online softmax with defer-max (rescale only when max grows by >6)
        float pm[4];
        #pragma unroll
        for (int r = 0; r < 4; r++) {
            float v = fmaxf(fmaxf(S[0][r], S[1][r]), fmaxf(S[2][r], S[3][r]));
            #pragma unroll
            for (int off = 1; off < 16; off <<= 1) v = fmaxf(v, __shfl_xor(v, off));
            pm[r] = v;
        }
        bool grow = (pm[0] > mrun[0] + 6.f) | (pm[1] > mrun[1] + 6.f) |
                    (pm[2] > mrun[2] + 6.f) | (pm[3] > mrun[3] + 6.f);
        if (__any(grow)) {
            #pragma unroll
            for (int r = 0; r < 4; r++) {
                float mnew  = fmaxf(mrun[r], pm[r]);
                float alpha = __expf(mrun[r] - mnew);
                mrun[r] = mnew;
                #pragma unroll
                for (int cf = 0; cf < 8; cf++) y[cf][r] *= alpha;
                lrun[r] *= alpha;
            }
        }
        #pragma unroll
        for (int r = 0; r < 4; r++) {
            float rs = 0.f;
            #pragma unroll
            for (int mf = 0; mf < 4; mf++) {
                float p = __expf(S[mf][r] - mrun[r]);
                S[mf][r] = p;
                rs += p;
            }
            #pragma unroll
            for (int off = 1; off < 16; off <<= 1) rs += __shfl_xor(rs, off);
            lrun[r] += rs;
        }

        // P (C-layout) -> per-wave LDS (A-layout), chunk-XOR swizzle
        #pragma unroll
        for (int mf = 0; mf < 4; mf++)
            #pragma unroll
            for (int r = 0; r < 4; r++) {
                int row = lh * 4 + r;
                int col = mf * 16 + l15;
                sPw[row * 64 + (((col >> 3) ^ (row & 7)) << 3) + (col & 7)] = f2bf(S[mf][r]);
            }

        // y += P @ V^T
        #pragma unroll
        for (int ks2 = 0; ks2 < 2; ks2++) {
            int jj = ks2 * 4 + lh;
            bf16x8 pa = *(const bf16x8*)&sPw[l15 * 64 + ((jj ^ (l15 & 7)) << 3)];
            __builtin_amdgcn_s_setprio(1);
            #pragma unroll
            for (int cf = 0; cf < 8; cf++) {
                int crow = cf * 16 + l15;
                bf16x8 vf = *(const bf16x8*)&cV[crow * 64 + ((jj ^ (crow & 7)) << 3)];
                y[cf] = __builtin_amdgcn_mfma_f32_16x16x32_bf16(pa, vf, y[cf], 0, 0, 0);
            }
            __builtin_amdgcn_s_setprio(0);
        }

        __syncthreads();
        cur ^= 1;
    }

    // epilogue
    float inv[4];
    #pragma unroll
    for (int r = 0; r < 4; r++) inv[r] = 1.f / lrun[r];
    #pragma unroll
    for (int cf = 0; cf < 8; cf++) {
        int c = cf * 16 + l15;
        #pragma unroll
        for (int r = 0; r < 4; r++)
            Ybuf[((size_t)b * 4096 + n0 + lh * 4 + r) * 128 + c] = f2bf(y[cf][r] * inv[r]);
    }
}

// ---------------- K4: wy = Ww @ y^T (+bias) + BN partial stats ----------------
// wy[b][o][n] bf16; stats[o*2]=sum, stats[o*2+1]=sumsq (atomic, fp32)
__global__ __launch_bounds__(256) void k4_wy(const short* __restrict__ Ww16,
        const short* __restrict__ Ybuf, const float* __restrict__ bw,
        short* __restrict__ wy, float* __restrict__ stats) {
    __shared__ float sums[4][64][2];
    const int nt = blockIdx.x;     // 16
    const int ot = blockIdx.y;     // 4
    const int b  = blockIdx.z;
    const int tid = threadIdx.x;
    const int lane = tid & 63, wave = tid >> 6;
    const int l15 = lane & 15, lh = lane >> 4;
    const int ob = ot * 64;
    const int nb = nt * 256 + wave * 64;

    bf16x8 aw[4][4];
    #pragma unroll
    for (int of = 0; of < 4; of++)
        #pragma unroll
        for (int ks = 0; ks < 4; ks++)
            aw[of][ks] = *(const bf16x8*)(Ww16 + (size_t)(ob + of * 16 + l15) * 128 + ks * 32 + lh * 8);

    f32x4 acc[4][4];               // [of][nf]
    #pragma unroll
    for (int i = 0; i < 4; i++)
        #pragma unroll
        for (int j = 0; j < 4; j++) acc[i][j] = f32x4{0.f, 0.f, 0.f, 0.f};

    #pragma unroll
    for (int nf = 0; nf < 4; nf++) {
        bf16x8 by[4];
        #pragma unroll
        for (int ks = 0; ks < 4; ks++)
            by[ks] = *(const bf16x8*)(Ybuf + ((size_t)b * 4096 + nb + nf * 16 + l15) * 128 + ks * 32 + lh * 8);
        #pragma unroll
        for (int of = 0; of < 4; of++)
            #pragma unroll
            for (int ks = 0; ks < 4; ks++)
                acc[of][nf] = __builtin_amdgcn_mfma_f32_16x16x32_bf16(aw[of][ks], by[ks], acc[of][nf], 0, 0, 0);
    }

    #pragma unroll
    for (int of = 0; of < 4; of++) {
        #pragma unroll
        for (int r = 0; r < 4; r++) {
            int o = ob + of * 16 + lh * 4 + r;
            float bias = bw[o];
            float s = 0.f, s2 = 0.f;
            #pragma unroll
            for (int nf = 0; nf < 4; nf++) {
                float v = acc[of][nf][r] + bias;
                wy[((size_t)b * 256 + o) * 4096 + nb + nf * 16 + l15] = f2bf(v);
                s += v; s2 += v * v;
            }
            #pragma unroll
            for (int off = 1; off < 16; off <<= 1) { s += __shfl_xor(s, off); s2 += __shfl_xor(s2, off); }
            if (l15 == 0) {
                sums[wave][of * 16 + lh * 4 + r][0] = s;
                sums[wave][of * 16 + lh * 4 + r][1] = s2;
            }
        }
    }
    __syncthreads();
    if (tid < 64) {
        float s  = sums[0][tid][0] + sums[1][tid][0] + sums[2][tid][0] + sums[3][tid][0];
        float s2 = sums[0][tid][1] + sums[1][tid][1] + sums[2][tid][1] + sums[3][tid][1];
        atomicAdd(&stats[(ob + tid) * 2], s);
        atomicAdd(&stats[(ob + tid) * 2 + 1], s2);
    }
}

// ---------------- K4b: finalize mean / rstd ----------------
__global__ __launch_bounds__(256) void k4b_stats(const float* __restrict__ stats, float* __restrict__ ms) {
    int o = threadIdx.x;
    float mean = stats[o * 2] * (1.f / 32768.f);
    float var  = stats[o * 2 + 1] * (1.f / 32768.f) - mean * mean;
    ms[o * 2] = mean;
    ms[o * 2 + 1] = rsqrtf(var + 1e-5f);
}

// ---------------- K5: BN apply + residual + global spatial max ----------------
__global__ __launch_bounds__(256) void k5_bnmax(const short* __restrict__ wy,
        const float* __restrict__ x, const float* __restrict__ ms,
        const float* __restrict__ gamma, const float* __restrict__ beta,
        float* __restrict__ outp) {
    int b = blockIdx.x >> 8;
    int o = blockIdx.x & 255;
    int tid = threadIdx.x;
    float mean = ms[o * 2], rstd = ms[o * 2 + 1];
    float A = rstd * gamma[o];
    float B = beta[o] - mean * A;
    const short* pw = wy + ((size_t)b * 256 + o) * 4096;
    const float* px = x + ((size_t)b * 256 + o) * 4096;
    float mx = -1e30f;
    #pragma unroll
    for (int j = 0; j < 2; j++) {
        int e = (tid + j * 256) * 8;
        bf16x8 w8 = *(const bf16x8*)(pw + e);
        float4 xa = *(const float4*)(px + e);
        float4 xb = *(const float4*)(px + e + 4);
        mx = fmaxf(mx, bf2f(w8[0]) * A + B + xa.x);
        mx = fmaxf(mx, bf2f(w8[1]) * A + B + xa.y);
        mx = fmaxf(mx, bf2f(w8[2]) * A + B + xa.z);
        mx = fmaxf(mx, bf2f(w8[3]) * A + B + xa.w);
        mx = fmaxf(mx, bf2f(w8[4]) * A + B + xb.x);
        mx = fmaxf(mx, bf2f(w8[5]) * A + B + xb.y);
        mx = fmaxf(mx, bf2f(w8[6]) * A + B + xb.z);
        mx = fmaxf(mx, bf2f(w8[7]) * A + B + xb.w);
    }
    #pragma unroll
    for (int off = 1; off < 64; off <<= 1) mx = fmaxf(mx, __shfl_xor(mx, off));
    __shared__ float red[4];
    if ((tid & 63) == 0) red[tid >> 6] = mx;
    __syncthreads();
    if (tid == 0)
        outp[b * 256 + o] = fmaxf(fmaxf(red[0], red[1]), fmaxf(red[2], red[3]));
}

extern "C" void kernel_launch(void* const* d_in, const int* in_sizes, int n_in,
                              void* d_out, int out_size, void* d_ws, size_t ws_size,
                              hipStream_t stream) {
    const float* x     = (const float*)d_in[0];
    const float* Wg    = (const float*)d_in[1];
    const float* bg    = (const float*)d_in[2];
    const float* Wt    = (const float*)d_in[3];
    const float* bt    = (const float*)d_in[4];
    const float* Wp    = (const float*)d_in[5];
    const float* bp    = (const float*)d_in[6];
    const float* Ww    = (const float*)d_in[7];
    const float* bw    = (const float*)d_in[8];
    const float* gamma = (const float*)d_in[9];
    const float* beta  = (const float*)d_in[10];
    float* outp = (float*)d_out;

    char* ws = (char*)d_ws;
    size_t off = 0;
    auto alloc = [&](size_t bytes) -> void* {
        void* p = ws + off;
        off = (off + bytes + 255) & ~(size_t)255;
        return p;
    };
    short* W_all = (short*)alloc((size_t)384 * 256 * 2);
    short* Ww16  = (short*)alloc((size_t)256 * 128 * 2);
    float* b_all = (float*)alloc((size_t)384 * 4);
    short* Out   = (short*)alloc((size_t)8 * 4096 * 384 * 2);
    short* Kmat  = (short*)alloc((size_t)8 * 1024 * 128 * 2);
    short* Vmat  = (short*)alloc((size_t)8 * 128 * 1024 * 2);
    short* Ybuf  = (short*)alloc((size_t)8 * 4096 * 128 * 2);
    short* wy    = (short*)alloc((size_t)8 * 256 * 4096 * 2);
    float* stats = (float*)alloc((size_t)256 * 2 * 4);
    float* ms    = (float*)alloc((size_t)256 * 2 * 4);

    hipMemsetAsync(stats, 0, 256 * 2 * 4, stream);

    k0_prep<<<512, 256, 0, stream>>>(Wg, Wt, Wp, bg, bt, bp, Ww, W_all, Ww16, b_all);
    k1_conv<<<dim3(32, 3, 8), 256, 0, stream>>>(x, W_all, b_all, Out);
    k2a_poolK<<<512, 256, 0, stream>>>(Out, Kmat);
    k2b_poolV<<<256, 256, 0, stream>>>(Out, Vmat);
    k3_attn<<<256, 512, 0, stream>>>(Out, Kmat, Vmat, Ybuf);
    k4_wy<<<dim3(16, 4, 8), 256, 0, stream>>>(Ww16, Ybuf, bw, wy, stats);
    k4b_stats<<<1, 256, 0, stream>>>(stats, ms);
    k5_bnmax<<<2048, 256, 0, stream>>>(wy, x, ms, gamma, beta, outp);
}

// Round 5
// 125.830 us; speedup vs baseline: 1.1234x; 1.1234x over previous
//
#include <hip/hip_runtime.h>
#include <hip/hip_bf16.h>
#include <stdint.h>

using f32x4  = __attribute__((ext_vector_type(4))) float;
using bf16x8 = __attribute__((ext_vector_type(8))) short;
using short4v = __attribute__((ext_vector_type(4))) short;

#define DEVINL static __device__ __forceinline__

DEVINL short f2bf(float f) {
    union { float f; uint32_t u; } v; v.f = f;
    uint32_t r = (v.u + 0x7FFFu + ((v.u >> 16) & 1u)) >> 16;   // RNE
    return (short)(uint16_t)r;
}
DEVINL float bf2f(short s) {
    union { uint32_t u; float f; } v; v.u = ((uint32_t)(uint16_t)s) << 16;
    return v.f;
}

// async global -> LDS, 16B per lane. LDS dest is wave-uniform base + lane*16 (HW).
DEVINL void gld16(const short* g, short* l) {
    __builtin_amdgcn_global_load_lds(
        (const __attribute__((address_space(1))) unsigned int*)g,
        (__attribute__((address_space(3))) unsigned int*)l, 16, 0, 0);
}

// ---------------- K0: weight prep (fp32 -> bf16, stack Wg|Wt|Wp) ----------------
__global__ __launch_bounds__(256) void k0_prep(
        const float* __restrict__ Wg, const float* __restrict__ Wt, const float* __restrict__ Wp,
        const float* __restrict__ bg, const float* __restrict__ bt, const float* __restrict__ bp,
        const float* __restrict__ Ww,
        short* __restrict__ W_all, short* __restrict__ Ww16, float* __restrict__ b_all) {
    int i = blockIdx.x * 256 + threadIdx.x;
    if (i < 384 * 256) {
        int r = i >> 8, c = i & 255;
        float v = (r < 128) ? Wg[r * 256 + c] : (r < 256) ? Wt[(r - 128) * 256 + c] : Wp[(r - 256) * 256 + c];
        W_all[i] = f2bf(v);
    } else if (i < 384 * 256 + 256 * 128) {
        int j = i - 384 * 256;
        Ww16[j] = f2bf(Ww[j]);
    }
    if (i < 384) {
        b_all[i] = (i < 128) ? bg[i] : (i < 256) ? bt[i - 128] : bp[i - 256];
    }
}

// ---------------- K1: fused conv1x1 x3 GEMM ----------------
__global__ __launch_bounds__(256) void k1_conv(const float* __restrict__ x,
        const short* __restrict__ W_all, const float* __restrict__ b_all,
        short* __restrict__ Out) {
    __shared__ short xs[128 * 40];          // [n(128)][c(32)+pad8]
    const int ntile = blockIdx.x;           // 32
    const int otile = blockIdx.y;           // 3
    const int b     = blockIdx.z;           // 8
    const int tid  = threadIdx.x;
    const int lane = tid & 63;
    const int wave = tid >> 6;
    const int wn = wave >> 1, wo = wave & 1;
    const int l15 = lane & 15, lh = lane >> 4;

    f32x4 acc[4][4];
    #pragma unroll
    for (int i = 0; i < 4; i++)
        #pragma unroll
        for (int j = 0; j < 4; j++) acc[i][j] = f32x4{0.f, 0.f, 0.f, 0.f};

    const int n0 = ntile * 128;
    const int ob = otile * 128 + wo * 64;
    const float* xb = x + (size_t)b * 256 * 4096;

    for (int kt = 0; kt < 8; kt++) {
        __syncthreads();
        #pragma unroll
        for (int p = 0; p < 4; p++) {
            int c  = p * 8 + (tid >> 5);
            int n4 = (tid & 31) * 4;
            const float4 v = *(const float4*)(xb + (size_t)(kt * 32 + c) * 4096 + n0 + n4);
            xs[(n4 + 0) * 40 + c] = f2bf(v.x);
            xs[(n4 + 1) * 40 + c] = f2bf(v.y);
            xs[(n4 + 2) * 40 + c] = f2bf(v.z);
            xs[(n4 + 3) * 40 + c] = f2bf(v.w);
        }
        __syncthreads();

        bf16x8 a[4], w[4];
        #pragma unroll
        for (int nf = 0; nf < 4; nf++)
            a[nf] = *(const bf16x8*)&xs[(wn * 64 + nf * 16 + l15) * 40 + lh * 8];
        #pragma unroll
        for (int of = 0; of < 4; of++)
            w[of] = *(const bf16x8*)(W_all + (size_t)(ob + of * 16 + l15) * 256 + kt * 32 + lh * 8);
        #pragma unroll
        for (int nf = 0; nf < 4; nf++)
            #pragma unroll
            for (int of = 0; of < 4; of++)
                acc[nf][of] = __builtin_amdgcn_mfma_f32_16x16x32_bf16(a[nf], w[of], acc[nf][of], 0, 0, 0);
    }

    #pragma unroll
    for (int of = 0; of < 4; of++) {
        int o = ob + of * 16 + l15;
        float bias = b_all[o];
        #pragma unroll
        for (int nf = 0; nf < 4; nf++)
            #pragma unroll
            for (int r = 0; r < 4; r++) {
                int n = n0 + wn * 64 + nf * 16 + lh * 4 + r;
                Out[((size_t)b * 4096 + n) * 384 + o] = f2bf(acc[nf][of][r] + bias);
            }
    }
}

// ---------------- K2a: maxpool phi -> Kmat[b][m][c] (bf16) ----------------
__global__ __launch_bounds__(256) void k2a_poolK(const short* __restrict__ Out, short* __restrict__ Kmat) {
    int t = blockIdx.x * 256 + threadIdx.x;
    int c8 = t & 15;
    int m  = (t >> 4) & 1023;
    int b  = t >> 14;
    int hp = m >> 5, wp = m & 31;
    int n0 = hp * 128 + wp * 2;
    const short* base = Out + (size_t)b * 4096 * 384 + 256 + c8 * 8;
    bf16x8 v0 = *(const bf16x8*)(base + (size_t)(n0) * 384);
    bf16x8 v1 = *(const bf16x8*)(base + (size_t)(n0 + 1) * 384);
    bf16x8 v2 = *(const bf16x8*)(base + (size_t)(n0 + 64) * 384);
    bf16x8 v3 = *(const bf16x8*)(base + (size_t)(n0 + 65) * 384);
    bf16x8 vo;
    #pragma unroll
    for (int i = 0; i < 8; i++) {
        float mx = fmaxf(fmaxf(bf2f(v0[i]), bf2f(v1[i])), fmaxf(bf2f(v2[i]), bf2f(v3[i])));
        vo[i] = f2bf(mx);
    }
    *(bf16x8*)(Kmat + ((size_t)b * 1024 + m) * 128 + c8 * 8) = vo;
}

// ---------------- K2b: maxpool g -> Vmat[b][c][m] (bf16, transposed) ----------------
__global__ __launch_bounds__(256) void k2b_poolV(const short* __restrict__ Out, short* __restrict__ Vmat) {
    __shared__ short g[128 * 136];
    int b  = blockIdx.x >> 5;
    int hp = blockIdx.x & 31;
    int tid = threadIdx.x;
    {
        int nloc = tid >> 1;
        int ch0  = (tid & 1) * 8;
        const short* src = Out + ((size_t)b * 4096 + hp * 128 + nloc) * 384;
        #pragma unroll
        for (int i = 0; i < 8; i++) {
            int chunk = ch0 + i;
            *(bf16x8*)&g[nloc * 136 + chunk * 8] = *(const bf16x8*)(src + chunk * 8);
        }
    }
    __syncthreads();
    int wp = tid & 31;
    int cb = tid >> 5;
    #pragma unroll
    for (int pass = 0; pass < 16; pass++) {
        int c = pass * 8 + cb;
        float a0 = bf2f(g[(2 * wp) * 136 + c]);
        float a1 = bf2f(g[(2 * wp + 1) * 136 + c]);
        float a2 = bf2f(g[(64 + 2 * wp) * 136 + c]);
        float a3 = bf2f(g[(65 + 2 * wp) * 136 + c]);
        float mx = fmaxf(fmaxf(a0, a1), fmaxf(a2, a3));
        Vmat[((size_t)b * 128 + c) * 1024 + hp * 32 + wp] = f2bf(mx);
    }
}

// ---------------- K3: flash attention v5 ----------------
// R2 skeleton (4 waves x 16 rows, 512 blocks, dbuf gld16 staging) +
// counted-vmcnt raw-barrier pipeline (no drains) + swapped QK^T (lane-local softmax).
__global__ __launch_bounds__(256) void k3_attn(const short* __restrict__ Out,
        const short* __restrict__ Kmat, const short* __restrict__ Vmat,
        short* __restrict__ Ybuf) {
    __shared__ short sK[2][64 * 128];   // [m][c], chunk-XOR-swizzled content
    __shared__ short sV[2][128 * 64];   // [c][m], chunk-XOR-swizzled content
    __shared__ short sP[4][16 * 64];    // per-wave P (A-layout, 8B-subchunk swizzle)

    const int bid = blockIdx.x;         // 512
    const int b   = bid & 7;
    const int nt  = bid >> 3;           // 64 tiles of 64 rows
    const int tid = threadIdx.x;
    const int lane = tid & 63;
    const int wave = tid >> 6;
    const int l15 = lane & 15, lh = lane >> 4;
    const int n0 = nt * 64 + wave * 16;

    const short* Kb = Kmat + (size_t)b * 1024 * 128;
    const short* Vb = Vmat + (size_t)b * 128 * 1024;
    short* sPw = sP[wave];

    // stage one 64-wide m-tile (K: 64x128, V: 128x64): 8 gld16 per wave
    auto STAGE = [&](int t, int bufi) {
        const int m0 = t * 64;
        #pragma unroll
        for (int i = 0; i < 4; i++) {
            const int segb = (i * 4 + wave) * 64;          // wave-uniform, chunk units
            const int rowK = (segb >> 4) + (lane >> 4);
            const int chkK = lane & 15;
            gld16(Kb + (size_t)(m0 + rowK) * 128 + ((chkK ^ (rowK & 15)) << 3),
                  &sK[bufi][segb * 8]);
            const int rowV = (segb >> 3) + (lane >> 3);
            const int chkV = lane & 7;
            gld16(Vb + (size_t)rowV * 1024 + m0 + ((chkV ^ (rowV & 7)) << 3),
                  &sV[bufi][segb * 8]);
        }
    };

    bf16x8 q[4];
    {
        const short* qrow = Out + ((size_t)b * 4096 + n0 + l15) * 384 + 128;
        #pragma unroll
        for (int ks = 0; ks < 4; ks++)
            q[ks] = *(const bf16x8*)(qrow + ks * 32 + lh * 8);
    }

    f32x4 y[8];
    #pragma unroll
    for (int cf = 0; cf < 8; cf++) y[cf] = f32x4{0.f, 0.f, 0.f, 0.f};
    float mrun = -1e30f, lrun = 0.f;    // per-lane: q-row = l15 (replicated over lh)

    STAGE(0, 0);
    int cur = 0;

    for (int t = 0; t < 16; t++) {
        if (t < 15) {
            STAGE(t + 1, cur ^ 1);
            asm volatile("s_waitcnt vmcnt(8)" ::: "memory");   // tile-t loads done, t+1 in flight
        } else {
            asm volatile("s_waitcnt vmcnt(0)" ::: "memory");
        }
        __builtin_amdgcn_s_barrier();
        __builtin_amdgcn_sched_barrier(0);

        const short* cK = sK[cur];
        const short* cV = sV[cur];

        // S^T = K Q^T : lane holds q-row = l15, m = mf*16 + lh*4 + r
        f32x4 S[4];
        #pragma unroll
        for (int mf = 0; mf < 4; mf++) S[mf] = f32x4{0.f, 0.f, 0.f, 0.f};
        #pragma unroll
        for (int ks = 0; ks < 4; ks++) {
            bf16x8 kf[4];
            #pragma unroll
            for (int mf = 0; mf < 4; mf++) {
                int mrow = mf * 16 + l15;
                int jj   = ks * 4 + lh;
                kf[mf] = *(const bf16x8*)&cK[mrow * 128 + ((jj ^ (mrow & 15)) << 3)];
            }
            __builtin_amdgcn_s_setprio(1);
            #pragma unroll
            for (int mf = 0; mf < 4; mf++)
                S[mf] = __builtin_amdgcn_mfma_f32_16x16x32_bf16(kf[mf], q[ks], S[mf], 0, 0, 0);
            __builtin_amdgcn_s_setprio(0);
        }

        // lane-local softmax: in-register 16-max + 2-step cross-lh shfl
        float pm = S[0][0];
        #pragma unroll
        for (int mf = 0; mf < 4; mf++)
            #pragma unroll
            for (int r = 0; r < 4; r++) pm = fmaxf(pm, S[mf][r]);
        pm = fmaxf(pm, __shfl_xor(pm, 16));
        pm = fmaxf(pm, __shfl_xor(pm, 32));

        if (__any(pm > mrun + 6.f)) {          // defer-max
            float mnew  = fmaxf(mrun, pm);
            float alpha = __expf(mrun - mnew);
            mrun = mnew;
            lrun *= alpha;
            float aR[4];
            #pragma unroll
            for (int r = 0; r < 4; r++) aR[r] = __shfl(alpha, lh * 4 + r);
            #pragma unroll
            for (int cf = 0; cf < 8; cf++)
                #pragma unroll
                for (int r = 0; r < 4; r++) y[cf][r] *= aR[r];
        }
        float rs = 0.f;
        #pragma unroll
        for (int mf = 0; mf < 4; mf++)
            #pragma unroll
            for (int r = 0; r < 4; r++) {
                float p = __expf(S[mf][r] - mrun);
                S[mf][r] = p;
                rs += p;
            }
        rs += __shfl_xor(rs, 16);
        rs += __shfl_xor(rs, 32);
        lrun += rs;

        // P -> per-wave LDS, vectorized 8B writes, 8B-subchunk XOR swizzle
        #pragma unroll
        for (int mf = 0; mf < 4; mf++) {
            short4v pk = { f2bf(S[mf][0]), f2bf(S[mf][1]), f2bf(S[mf][2]), f2bf(S[mf][3]) };
            *(short4v*)&sPw[(l15 << 6) + (((mf * 4 + lh) ^ l15) << 2)] = pk;
        }

        // y += P @ V^T
        #pragma unroll
        for (int ks2 = 0; ks2 < 2; ks2++) {
            int u0 = ks2 * 8 + lh * 2;
            short4v lo = *(const short4v*)&sPw[(l15 << 6) + (((u0)     ^ l15) << 2)];
            short4v hi = *(const short4v*)&sPw[(l15 << 6) + (((u0 + 1) ^ l15) << 2)];
            bf16x8 pa = { lo.x, lo.y, lo.z, lo.w, hi.x, hi.y, hi.z, hi.w };
            int jj = ks2 * 4 + lh;
            __builtin_amdgcn_s_setprio(1);
            #pragma unroll
            for (int cf = 0; cf < 8; cf++) {
                int crow = cf * 16 + l15;
                bf16x8 vf = *(const bf16x8*)&cV[crow * 64 + ((jj ^ (crow & 7)) << 3)];
                y[cf] = __builtin_amdgcn_mfma_f32_16x16x32_bf16(pa, vf, y[cf], 0, 0, 0);
            }
            __builtin_amdgcn_s_setprio(0);
        }

        __builtin_amdgcn_sched_barrier(0);
        __builtin_amdgcn_s_barrier();       // protect buf[cur] from next-iter overwrite
        cur ^= 1;
    }

    // epilogue: divide by row-sum (row n = lh*4+r lives in lane l15 = n)
    float linv[4];
    #pragma unroll
    for (int r = 0; r < 4; r++) linv[r] = 1.f / __shfl(lrun, lh * 4 + r);
    #pragma unroll
    for (int cf = 0; cf < 8; cf++) {
        int c = cf * 16 + l15;
        #pragma unroll
        for (int r = 0; r < 4; r++)
            Ybuf[((size_t)b * 4096 + n0 + lh * 4 + r) * 128 + c] = f2bf(y[cf][r] * linv[r]);
    }
}

// ---------------- K4: wy = Ww @ y^T (+bias) + BN partial stats ----------------
__global__ __launch_bounds__(256) void k4_wy(const short* __restrict__ Ww16,
        const short* __restrict__ Ybuf, const float* __restrict__ bw,
        short* __restrict__ wy, float* __restrict__ stats) {
    __shared__ float sums[4][64][2];
    const int nt = blockIdx.x;     // 16
    const int ot = blockIdx.y;     // 4
    const int b  = blockIdx.z;
    const int tid = threadIdx.x;
    const int lane = tid & 63, wave = tid >> 6;
    const int l15 = lane & 15, lh = lane >> 4;
    const int ob = ot * 64;
    const int nb = nt * 256 + wave * 64;

    bf16x8 aw[4][4];
    #pragma unroll
    for (int of = 0; of < 4; of++)
        #pragma unroll
        for (int ks = 0; ks < 4; ks++)
            aw[of][ks] = *(const bf16x8*)(Ww16 + (size_t)(ob + of * 16 + l15) * 128 + ks * 32 + lh * 8);

    f32x4 acc[4][4];               // [of][nf]
    #pragma unroll
    for (int i = 0; i < 4; i++)
        #pragma unroll
        for (int j = 0; j < 4; j++) acc[i][j] = f32x4{0.f, 0.f, 0.f, 0.f};

    #pragma unroll
    for (int nf = 0; nf < 4; nf++) {
        bf16x8 by[4];
        #pragma unroll
        for (int ks = 0; ks < 4; ks++)
            by[ks] = *(const bf16x8*)(Ybuf + ((size_t)b * 4096 + nb + nf * 16 + l15) * 128 + ks * 32 + lh * 8);
        #pragma unroll
        for (int of = 0; of < 4; of++)
            #pragma unroll
            for (int ks = 0; ks < 4; ks++)
                acc[of][nf] = __builtin_amdgcn_mfma_f32_16x16x32_bf16(aw[of][ks], by[ks], acc[of][nf], 0, 0, 0);
    }

    #pragma unroll
    for (int of = 0; of < 4; of++) {
        #pragma unroll
        for (int r = 0; r < 4; r++) {
            int o = ob + of * 16 + lh * 4 + r;
            float bias = bw[o];
            float s = 0.f, s2 = 0.f;
            #pragma unroll
            for (int nf = 0; nf < 4; nf++) {
                float v = acc[of][nf][r] + bias;
                wy[((size_t)b * 256 + o) * 4096 + nb + nf * 16 + l15] = f2bf(v);
                s += v; s2 += v * v;
            }
            #pragma unroll
            for (int off = 1; off < 16; off <<= 1) { s += __shfl_xor(s, off); s2 += __shfl_xor(s2, off); }
            if (l15 == 0) {
                sums[wave][of * 16 + lh * 4 + r][0] = s;
                sums[wave][of * 16 + lh * 4 + r][1] = s2;
            }
        }
    }
    __syncthreads();
    if (tid < 64) {
        float s  = sums[0][tid][0] + sums[1][tid][0] + sums[2][tid][0] + sums[3][tid][0];
        float s2 = sums[0][tid][1] + sums[1][tid][1] + sums[2][tid][1] + sums[3][tid][1];
        atomicAdd(&stats[(ob + tid) * 2], s);
        atomicAdd(&stats[(ob + tid) * 2 + 1], s2);
    }
}

// ---------------- K4b: finalize mean / rstd ----------------
__global__ __launch_bounds__(256) void k4b_stats(const float* __restrict__ stats, float* __restrict__ ms) {
    int o = threadIdx.x;
    float mean = stats[o * 2] * (1.f / 32768.f);
    float var  = stats[o * 2 + 1] * (1.f / 32768.f) - mean * mean;
    ms[o * 2] = mean;
    ms[o * 2 + 1] = rsqrtf(var + 1e-5f);
}

// ---------------- K5: BN apply + residual + global spatial max ----------------
__global__ __launch_bounds__(256) void k5_bnmax(const short* __restrict__ wy,
        const float* __restrict__ x, const float* __restrict__ ms,
        const float* __restrict__ gamma, const float* __restrict__ beta,
        float* __restrict__ outp) {
    int b = blockIdx.x >> 8;
    int o = blockIdx.x & 255;
    int tid = threadIdx.x;
    float mean = ms[o * 2], rstd = ms[o * 2 + 1];
    float A = rstd * gamma[o];
    float B = beta[o] - mean * A;
    const short* pw = wy + ((size_t)b * 256 + o) * 4096;
    const float* px = x + ((size_t)b * 256 + o) * 4096;
    float mx = -1e30f;
    #pragma unroll
    for (int j = 0; j < 2; j++) {
        int e = (tid + j * 256) * 8;
        bf16x8 w8 = *(const bf16x8*)(pw + e);
        float4 xa = *(const float4*)(px + e);
        float4 xb = *(const float4*)(px + e + 4);
        mx = fmaxf(mx, bf2f(w8[0]) * A + B + xa.x);
        mx = fmaxf(mx, bf2f(w8[1]) * A + B + xa.y);
        mx = fmaxf(mx, bf2f(w8[2]) * A + B + xa.z);
        mx = fmaxf(mx, bf2f(w8[3]) * A + B + xa.w);
        mx = fmaxf(mx, bf2f(w8[4]) * A + B + xb.x);
        mx = fmaxf(mx, bf2f(w8[5]) * A + B + xb.y);
        mx = fmaxf(mx, bf2f(w8[6]) * A + B + xb.z);
        mx = fmaxf(mx, bf2f(w8[7]) * A + B + xb.w);
    }
    #pragma unroll
    for (int off = 1; off < 64; off <<= 1) mx = fmaxf(mx, __shfl_xor(mx, off));
    __shared__ float red[4];
    if ((tid & 63) == 0) red[tid >> 6] = mx;
    __syncthreads();
    if (tid == 0)
        outp[b * 256 + o] = fmaxf(fmaxf(red[0], red[1]), fmaxf(red[2], red[3]));
}

extern "C" void kernel_launch(void* const* d_in, const int* in_sizes, int n_in,
                              void* d_out, int out_size, void* d_ws, size_t ws_size,
                              hipStream_t stream) {
    const float* x     = (const float*)d_in[0];
    const float* Wg    = (const float*)d_in[1];
    const float* bg    = (const float*)d_in[2];
    const float* Wt    = (const float*)d_in[3];
    const float* bt    = (const float*)d_in[4];
    const float* Wp    = (const float*)d_in[5];
    const float* bp    = (const float*)d_in[6];
    const float* Ww    = (const float*)d_in[7];
    const float* bw    = (const float*)d_in[8];
    const float* gamma = (const float*)d_in[9];
    const float* beta  = (const float*)d_in[10];
    float* outp = (float*)d_out;

    char* ws = (char*)d_ws;
    size_t off = 0;
    auto alloc = [&](size_t bytes) -> void* {
        void* p = ws + off;
        off = (off + bytes + 255) & ~(size_t)255;
        return p;
    };
    short* W_all = (short*)alloc((size_t)384 * 256 * 2);
    short* Ww16  = (short*)alloc((size_t)256 * 128 * 2);
    float* b_all = (float*)alloc((size_t)384 * 4);
    short* Out   = (short*)alloc((size_t)8 * 4096 * 384 * 2);
    short* Kmat  = (short*)alloc((size_t)8 * 1024 * 128 * 2);
    short* Vmat  = (short*)alloc((size_t)8 * 128 * 1024 * 2);
    short* Ybuf  = (short*)alloc((size_t)8 * 4096 * 128 * 2);
    short* wy    = (short*)alloc((size_t)8 * 256 * 4096 * 2);
    float* stats = (float*)alloc((size_t)256 * 2 * 4);
    float* ms    = (float*)alloc((size_t)256 * 2 * 4);

    hipMemsetAsync(stats, 0, 256 * 2 * 4, stream);

    k0_prep<<<512, 256, 0, stream>>>(Wg, Wt, Wp, bg, bt, bp, Ww, W_all, Ww16, b_all);
    k1_conv<<<dim3(32, 3, 8), 256, 0, stream>>>(x, W_all, b_all, Out);
    k2a_poolK<<<512, 256, 0, stream>>>(Out, Kmat);
    k2b_poolV<<<256, 256, 0, stream>>>(Out, Vmat);
    k3_attn<<<512, 256, 0, stream>>>(Out, Kmat, Vmat, Ybuf);
    k4_wy<<<dim3(16, 4, 8), 256, 0, stream>>>(Ww16, Ybuf, bw, wy, stats);
    k4b_stats<<<1, 256, 0, stream>>>(stats, ms);
    k5_bnmax<<<2048, 256, 0, stream>>>(wy, x, ms, gamma, beta, outp);
}

// Round 6
// 114.248 us; speedup vs baseline: 1.2373x; 1.1014x over previous
//
#include <hip/hip_runtime.h>
#include <hip/hip_bf16.h>
#include <stdint.h>

using f32x4  = __attribute__((ext_vector_type(4))) float;
using bf16x8 = __attribute__((ext_vector_type(8))) short;
using short4v = __attribute__((ext_vector_type(4))) short;

#define DEVINL static __device__ __forceinline__

DEVINL short f2bf(float f) {
    union { float f; uint32_t u; } v; v.f = f;
    uint32_t r = (v.u + 0x7FFFu + ((v.u >> 16) & 1u)) >> 16;   // RNE
    return (short)(uint16_t)r;
}
DEVINL float bf2f(short s) {
    union { uint32_t u; float f; } v; v.u = ((uint32_t)(uint16_t)s) << 16;
    return v.f;
}

// async global -> LDS, 16B per lane. LDS dest is wave-uniform base + lane*16 (HW).
DEVINL void gld16(const short* g, short* l) {
    __builtin_amdgcn_global_load_lds(
        (const __attribute__((address_space(1))) unsigned int*)g,
        (__attribute__((address_space(3))) unsigned int*)l, 16, 0, 0);
}

// ---------------- K0: weight prep (fp32 -> bf16, stack Wg|Wt|Wp) ----------------
__global__ __launch_bounds__(256) void k0_prep(
        const float* __restrict__ Wg, const float* __restrict__ Wt, const float* __restrict__ Wp,
        const float* __restrict__ bg, const float* __restrict__ bt, const float* __restrict__ bp,
        const float* __restrict__ Ww,
        short* __restrict__ W_all, short* __restrict__ Ww16, float* __restrict__ b_all) {
    int i = blockIdx.x * 256 + threadIdx.x;
    if (i < 384 * 256) {
        int r = i >> 8, c = i & 255;
        float v = (r < 128) ? Wg[r * 256 + c] : (r < 256) ? Wt[(r - 128) * 256 + c] : Wp[(r - 256) * 256 + c];
        W_all[i] = f2bf(v);
    } else if (i < 384 * 256 + 256 * 128) {
        int j = i - 384 * 256;
        Ww16[j] = f2bf(Ww[j]);
    }
    if (i < 384) {
        b_all[i] = (i < 128) ? bg[i] : (i < 256) ? bt[i - 128] : bp[i - 256];
    }
}

// ---------------- K1: fused conv1x1 x3 GEMM (v2: conflict-free LDS, vector epilogue) ----
// Out[b][n][o] (o in [0,384): 0..127=g, 128..255=theta, 256..383=phi), bf16
__global__ __launch_bounds__(256) void k1_conv(const float* __restrict__ x,
        const short* __restrict__ W_all, const float* __restrict__ b_all,
        short* __restrict__ Out) {
    __shared__ short xs[128 * 32];       // [n][c], 16B-chunk XOR swizzle: ch ^= (n>>1)&3
    __shared__ short obuf[128 * 128];    // [n][o], 16B-chunk XOR swizzle: ch ^= n&15
    const int ntile = blockIdx.x;           // 32
    const int otile = blockIdx.y;           // 3
    const int b     = blockIdx.z;           // 8
    const int tid  = threadIdx.x;
    const int lane = tid & 63;
    const int wave = tid >> 6;
    const int wn = wave >> 1, wo = wave & 1;
    const int l15 = lane & 15, lh = lane >> 4;

    f32x4 acc[4][4];
    #pragma unroll
    for (int i = 0; i < 4; i++)
        #pragma unroll
        for (int j = 0; j < 4; j++) acc[i][j] = f32x4{0.f, 0.f, 0.f, 0.f};

    const int n0 = ntile * 128;
    const int ob = otile * 128 + wo * 64;
    const float* xb = x + (size_t)b * 256 * 4096;

    // per-thread staging geometry: row along lanes (coalesced), 8 channels scalar
    const int srow_base = (lane & 15) + wave * 16;    // + p*64
    const int sc0 = (lane >> 4) * 8;                  // channel chunk base

    for (int kt = 0; kt < 8; kt++) {
        __syncthreads();
        #pragma unroll
        for (int p = 0; p < 2; p++) {
            int row = srow_base + p * 64;
            const float* xp = xb + (size_t)(kt * 32 + sc0) * 4096 + n0 + row;
            bf16x8 w8;
            #pragma unroll
            for (int j = 0; j < 8; j++) w8[j] = f2bf(xp[(size_t)j * 4096]);
            int ch = (sc0 >> 3) ^ ((row >> 1) & 3);
            *(bf16x8*)&xs[row * 32 + ch * 8] = w8;
        }
        __syncthreads();

        bf16x8 a[4], w[4];
        #pragma unroll
        for (int nf = 0; nf < 4; nf++) {
            int row = wn * 64 + nf * 16 + l15;
            int ch  = lh ^ ((row >> 1) & 3);
            a[nf] = *(const bf16x8*)&xs[row * 32 + ch * 8];
        }
        #pragma unroll
        for (int of = 0; of < 4; of++)
            w[of] = *(const bf16x8*)(W_all + (size_t)(ob + of * 16 + l15) * 256 + kt * 32 + lh * 8);
        #pragma unroll
        for (int nf = 0; nf < 4; nf++)
            #pragma unroll
            for (int of = 0; of < 4; of++)
                acc[nf][of] = __builtin_amdgcn_mfma_f32_16x16x32_bf16(a[nf], w[of], acc[nf][of], 0, 0, 0);
    }

    // epilogue: bias + bounce through XOR-swizzled obuf, then b128 stores
    #pragma unroll
    for (int of = 0; of < 4; of++) {
        int ocol = wo * 64 + of * 16 + l15;
        float bias = b_all[otile * 128 + ocol];
        #pragma unroll
        for (int nf = 0; nf < 4; nf++)
            #pragma unroll
            for (int r = 0; r < 4; r++) {
                int n  = wn * 64 + nf * 16 + lh * 4 + r;
                int ch = (ocol >> 3) ^ (n & 15);
                obuf[n * 128 + ch * 8 + (ocol & 7)] = f2bf(acc[nf][of][r] + bias);
            }
    }
    __syncthreads();
    #pragma unroll
    for (int p = 0; p < 8; p++) {
        int n  = wave * 4 + lh + p * 16;
        int ch = l15 ^ (n & 15);
        bf16x8 v = *(const bf16x8*)&obuf[n * 128 + ch * 8];
        *(bf16x8*)(Out + ((size_t)b * 4096 + n0 + n) * 384 + otile * 128 + l15 * 8) = v;
    }
}

// ---------------- K2a: maxpool phi -> Kmat[b][m][c] (bf16) ----------------
__global__ __launch_bounds__(256) void k2a_poolK(const short* __restrict__ Out, short* __restrict__ Kmat) {
    int t = blockIdx.x * 256 + threadIdx.x;
    int c8 = t & 15;
    int m  = (t >> 4) & 1023;
    int b  = t >> 14;
    int hp = m >> 5, wp = m & 31;
    int n0 = hp * 128 + wp * 2;
    const short* base = Out + (size_t)b * 4096 * 384 + 256 + c8 * 8;
    bf16x8 v0 = *(const bf16x8*)(base + (size_t)(n0) * 384);
    bf16x8 v1 = *(const bf16x8*)(base + (size_t)(n0 + 1) * 384);
    bf16x8 v2 = *(const bf16x8*)(base + (size_t)(n0 + 64) * 384);
    bf16x8 v3 = *(const bf16x8*)(base + (size_t)(n0 + 65) * 384);
    bf16x8 vo;
    #pragma unroll
    for (int i = 0; i < 8; i++) {
        float mx = fmaxf(fmaxf(bf2f(v0[i]), bf2f(v1[i])), fmaxf(bf2f(v2[i]), bf2f(v3[i])));
        vo[i] = f2bf(mx);
    }
    *(bf16x8*)(Kmat + ((size_t)b * 1024 + m) * 128 + c8 * 8) = vo;
}

// ---------------- K2b: maxpool g -> Vmat[b][c][m] (bf16, transposed) ----------------
__global__ __launch_bounds__(256) void k2b_poolV(const short* __restrict__ Out, short* __restrict__ Vmat) {
    __shared__ short g[128 * 136];
    int b  = blockIdx.x >> 5;
    int hp = blockIdx.x & 31;
    int tid = threadIdx.x;
    {
        int nloc = tid >> 1;
        int ch0  = (tid & 1) * 8;
        const short* src = Out + ((size_t)b * 4096 + hp * 128 + nloc) * 384;
        #pragma unroll
        for (int i = 0; i < 8; i++) {
            int chunk = ch0 + i;
            *(bf16x8*)&g[nloc * 136 + chunk * 8] = *(const bf16x8*)(src + chunk * 8);
        }
    }
    __syncthreads();
    int wp = tid & 31;
    int cb = tid >> 5;
    #pragma unroll
    for (int pass = 0; pass < 16; pass++) {
        int c = pass * 8 + cb;
        float a0 = bf2f(g[(2 * wp) * 136 + c]);
        float a1 = bf2f(g[(2 * wp + 1) * 136 + c]);
        float a2 = bf2f(g[(64 + 2 * wp) * 136 + c]);
        float a3 = bf2f(g[(65 + 2 * wp) * 136 + c]);
        float mx = fmaxf(fmaxf(a0, a1), fmaxf(a2, a3));
        Vmat[((size_t)b * 128 + c) * 1024 + hp * 32 + wp] = f2bf(mx);
    }
}

// ---------------- K3: flash attention v5 ----------------
// 4 waves x 16 rows, 512 blocks, dbuf gld16 staging, counted-vmcnt raw barriers,
// swapped QK^T (lane-local softmax), defer-max.
__global__ __launch_bounds__(256) void k3_attn(const short* __restrict__ Out,
        const short* __restrict__ Kmat, const short* __restrict__ Vmat,
        short* __restrict__ Ybuf) {
    __shared__ short sK[2][64 * 128];   // [m][c], chunk-XOR-swizzled content
    __shared__ short sV[2][128 * 64];   // [c][m], chunk-XOR-swizzled content
    __shared__ short sP[4][16 * 64];    // per-wave P (A-layout, 8B-subchunk swizzle)

    const int bid = blockIdx.x;         // 512
    const int b   = bid & 7;
    const int nt  = bid >> 3;           // 64 tiles of 64 rows
    const int tid = threadIdx.x;
    const int lane = tid & 63;
    const int wave = tid >> 6;
    const int l15 = lane & 15, lh = lane >> 4;
    const int n0 = nt * 64 + wave * 16;

    const short* Kb = Kmat + (size_t)b * 1024 * 128;
    const short* Vb = Vmat + (size_t)b * 128 * 1024;
    short* sPw = sP[wave];

    auto STAGE = [&](int t, int bufi) {
        const int m0 = t * 64;
        #pragma unroll
        for (int i = 0; i < 4; i++) {
            const int segb = (i * 4 + wave) * 64;          // wave-uniform, chunk units
            const int rowK = (segb >> 4) + (lane >> 4);
            const int chkK = lane & 15;
            gld16(Kb + (size_t)(m0 + rowK) * 128 + ((chkK ^ (rowK & 15)) << 3),
                  &sK[bufi][segb * 8]);
            const int rowV = (segb >> 3) + (lane >> 3);
            const int chkV = lane & 7;
            gld16(Vb + (size_t)rowV * 1024 + m0 + ((chkV ^ (rowV & 7)) << 3),
                  &sV[bufi][segb * 8]);
        }
    };

    bf16x8 q[4];
    {
        const short* qrow = Out + ((size_t)b * 4096 + n0 + l15) * 384 + 128;
        #pragma unroll
        for (int ks = 0; ks < 4; ks++)
            q[ks] = *(const bf16x8*)(qrow + ks * 32 + lh * 8);
    }

    f32x4 y[8];
    #pragma unroll
    for (int cf = 0; cf < 8; cf++) y[cf] = f32x4{0.f, 0.f, 0.f, 0.f};
    float mrun = -1e30f, lrun = 0.f;    // per-lane: q-row = l15 (replicated over lh)

    STAGE(0, 0);
    int cur = 0;

    for (int t = 0; t < 16; t++) {
        if (t < 15) {
            STAGE(t + 1, cur ^ 1);
            asm volatile("s_waitcnt vmcnt(8)" ::: "memory");
        } else {
            asm volatile("s_waitcnt vmcnt(0)" ::: "memory");
        }
        __builtin_amdgcn_s_barrier();
        __builtin_amdgcn_sched_barrier(0);

        const short* cK = sK[cur];
        const short* cV = sV[cur];

        // S^T = K Q^T : lane holds q-row = l15, m = mf*16 + lh*4 + r
        f32x4 S[4];
        #pragma unroll
        for (int mf = 0; mf < 4; mf++) S[mf] = f32x4{0.f, 0.f, 0.f, 0.f};
        #pragma unroll
        for (int ks = 0; ks < 4; ks++) {
            bf16x8 kf[4];
            #pragma unroll
            for (int mf = 0; mf < 4; mf++) {
                int mrow = mf * 16 + l15;
                int jj   = ks * 4 + lh;
                kf[mf] = *(const bf16x8*)&cK[mrow * 128 + ((jj ^ (mrow & 15)) << 3)];
            }
            __builtin_amdgcn_s_setprio(1);
            #pragma unroll
            for (int mf = 0; mf < 4; mf++)
                S[mf] = __builtin_amdgcn_mfma_f32_16x16x32_bf16(kf[mf], q[ks], S[mf], 0, 0, 0);
            __builtin_amdgcn_s_setprio(0);
        }

        // lane-local softmax
        float pm = S[0][0];
        #pragma unroll
        for (int mf = 0; mf < 4; mf++)
            #pragma unroll
            for (int r = 0; r < 4; r++) pm = fmaxf(pm, S[mf][r]);
        pm = fmaxf(pm, __shfl_xor(pm, 16));
        pm = fmaxf(pm, __shfl_xor(pm, 32));

        if (__any(pm > mrun + 6.f)) {          // defer-max
            float mnew  = fmaxf(mrun, pm);
            float alpha = __expf(mrun - mnew);
            mrun = mnew;
            lrun *= alpha;
            float aR[4];
            #pragma unroll
            for (int r = 0; r < 4; r++) aR[r] = __shfl(alpha, lh * 4 + r);
            #pragma unroll
            for (int cf = 0; cf < 8; cf++)
                #pragma unroll
                for (int r = 0; r < 4; r++) y[cf][r] *= aR[r];
        }
        float rs = 0.f;
        #pragma unroll
        for (int mf = 0; mf < 4; mf++)
            #pragma unroll
            for (int r = 0; r < 4; r++) {
                float p = __expf(S[mf][r] - mrun);
                S[mf][r] = p;
                rs += p;
            }
        rs += __shfl_xor(rs, 16);
        rs += __shfl_xor(rs, 32);
        lrun += rs;

        // P -> per-wave LDS, vectorized 8B writes, 8B-subchunk XOR swizzle
        #pragma unroll
        for (int mf = 0; mf < 4; mf++) {
            short4v pk = { f2bf(S[mf][0]), f2bf(S[mf][1]), f2bf(S[mf][2]), f2bf(S[mf][3]) };
            *(short4v*)&sPw[(l15 << 6) + (((mf * 4 + lh) ^ l15) << 2)] = pk;
        }

        // y += P @ V^T
        #pragma unroll
        for (int ks2 = 0; ks2 < 2; ks2++) {
            int u0 = ks2 * 8 + lh * 2;
            short4v lo = *(const short4v*)&sPw[(l15 << 6) + (((u0)     ^ l15) << 2)];
            short4v hi = *(const short4v*)&sPw[(l15 << 6) + (((u0 + 1) ^ l15) << 2)];
            bf16x8 pa = { lo.x, lo.y, lo.z, lo.w, hi.x, hi.y, hi.z, hi.w };
            int jj = ks2 * 4 + lh;
            __builtin_amdgcn_s_setprio(1);
            #pragma unroll
            for (int cf = 0; cf < 8; cf++) {
                int crow = cf * 16 + l15;
                bf16x8 vf = *(const bf16x8*)&cV[crow * 64 + ((jj ^ (crow & 7)) << 3)];
                y[cf] = __builtin_amdgcn_mfma_f32_16x16x32_bf16(pa, vf, y[cf], 0, 0, 0);
            }
            __builtin_amdgcn_s_setprio(0);
        }

        __builtin_amdgcn_sched_barrier(0);
        __builtin_amdgcn_s_barrier();       // protect buf[cur] from next-iter overwrite
        cur ^= 1;
    }

    // epilogue
    float linv[4];
    #pragma unroll
    for (int r = 0; r < 4; r++) linv[r] = 1.f / __shfl(lrun, lh * 4 + r);
    #pragma unroll
    for (int cf = 0; cf < 8; cf++) {
        int c = cf * 16 + l15;
        #pragma unroll
        for (int r = 0; r < 4; r++)
            Ybuf[((size_t)b * 4096 + n0 + lh * 4 + r) * 128 + c] = f2bf(y[cf][r] * linv[r]);
    }
}

// ---------------- K4: wy = Ww @ y^T (+bias) + BN partial stats ----------------
__global__ __launch_bounds__(256) void k4_wy(const short* __restrict__ Ww16,
        const short* __restrict__ Ybuf, const float* __restrict__ bw,
        short* __restrict__ wy, float* __restrict__ stats) {
    __shared__ float sums[4][64][2];
    const int nt = blockIdx.x;     // 16
    const int ot = blockIdx.y;     // 4
    const int b  = blockIdx.z;
    const int tid = threadIdx.x;
    const int lane = tid & 63, wave = tid >> 6;
    const int l15 = lane & 15, lh = lane >> 4;
    const int ob = ot * 64;
    const int nb = nt * 256 + wave * 64;

    bf16x8 aw[4][4];
    #pragma unroll
    for (int of = 0; of < 4; of++)
        #pragma unroll
        for (int ks = 0; ks < 4; ks++)
            aw[of][ks] = *(const bf16x8*)(Ww16 + (size_t)(ob + of * 16 + l15) * 128 + ks * 32 + lh * 8);

    f32x4 acc[4][4];               // [of][nf]
    #pragma unroll
    for (int i = 0; i < 4; i++)
        #pragma unroll
        for (int j = 0; j < 4; j++) acc[i][j] = f32x4{0.f, 0.f, 0.f, 0.f};

    #pragma unroll
    for (int nf = 0; nf < 4; nf++) {
        bf16x8 by[4];
        #pragma unroll
        for (int ks = 0; ks < 4; ks++)
            by[ks] = *(const bf16x8*)(Ybuf + ((size_t)b * 4096 + nb + nf * 16 + l15) * 128 + ks * 32 + lh * 8);
        #pragma unroll
        for (int of = 0; of < 4; of++)
            #pragma unroll
            for (int ks = 0; ks < 4; ks++)
                acc[of][nf] = __builtin_amdgcn_mfma_f32_16x16x32_bf16(aw[of][ks], by[ks], acc[of][nf], 0, 0, 0);
    }

    #pragma unroll
    for (int of = 0; of < 4; of++) {
        #pragma unroll
        for (int r = 0; r < 4; r++) {
            int o = ob + of * 16 + lh * 4 + r;
            float bias = bw[o];
            float s = 0.f, s2 = 0.f;
            #pragma unroll
            for (int nf = 0; nf < 4; nf++) {
                float v = acc[of][nf][r] + bias;
                wy[((size_t)b * 256 + o) * 4096 + nb + nf * 16 + l15] = f2bf(v);
                s += v; s2 += v * v;
            }
            #pragma unroll
            for (int off = 1; off < 16; off <<= 1) { s += __shfl_xor(s, off); s2 += __shfl_xor(s2, off); }
            if (l15 == 0) {
                sums[wave][of * 16 + lh * 4 + r][0] = s;
                sums[wave][of * 16 + lh * 4 + r][1] = s2;
            }
        }
    }
    __syncthreads();
    if (tid < 64) {
        float s  = sums[0][tid][0] + sums[1][tid][0] + sums[2][tid][0] + sums[3][tid][0];
        float s2 = sums[0][tid][1] + sums[1][tid][1] + sums[2][tid][1] + sums[3][tid][1];
        atomicAdd(&stats[(ob + tid) * 2], s);
        atomicAdd(&stats[(ob + tid) * 2 + 1], s2);
    }
}

// ---------------- K4b: finalize mean / rstd ----------------
__global__ __launch_bounds__(256) void k4b_stats(const float* __restrict__ stats, float* __restrict__ ms) {
    int o = threadIdx.x;
    float mean = stats[o * 2] * (1.f / 32768.f);
    float var  = stats[o * 2 + 1] * (1.f / 32768.f) - mean * mean;
    ms[o * 2] = mean;
    ms[o * 2 + 1] = rsqrtf(var + 1e-5f);
}

// ---------------- K5: BN apply + residual + global spatial max ----------------
__global__ __launch_bounds__(256) void k5_bnmax(const short* __restrict__ wy,
        const float* __restrict__ x, const float* __restrict__ ms,
        const float* __restrict__ gamma, const float* __restrict__ beta,
        float* __restrict__ outp) {
    int b = blockIdx.x >> 8;
    int o = blockIdx.x & 255;
    int tid = threadIdx.x;
    float mean = ms[o * 2], rstd = ms[o * 2 + 1];
    float A = rstd * gamma[o];
    float B = beta[o] - mean * A;
    const short* pw = wy + ((size_t)b * 256 + o) * 4096;
    const float* px = x + ((size_t)b * 256 + o) * 4096;
    float mx = -1e30f;
    #pragma unroll
    for (int j = 0; j < 2; j++) {
        int e = (tid + j * 256) * 8;
        bf16x8 w8 = *(const bf16x8*)(pw + e);
        float4 xa = *(const float4*)(px + e);
        float4 xb = *(const float4*)(px + e + 4);
        mx = fmaxf(mx, bf2f(w8[0]) * A + B + xa.x);
        mx = fmaxf(mx, bf2f(w8[1]) * A + B + xa.y);
        mx = fmaxf(mx, bf2f(w8[2]) * A + B + xa.z);
        mx = fmaxf(mx, bf2f(w8[3]) * A + B + xa.w);
        mx = fmaxf(mx, bf2f(w8[4]) * A + B + xb.x);
        mx = fmaxf(mx, bf2f(w8[5]) * A + B + xb.y);
        mx = fmaxf(mx, bf2f(w8[6]) * A + B + xb.z);
        mx = fmaxf(mx, bf2f(w8[7]) * A + B + xb.w);
    }
    #pragma unroll
    for (int off = 1; off < 64; off <<= 1) mx = fmaxf(mx, __shfl_xor(mx, off));
    __shared__ float red[4];
    if ((tid & 63) == 0) red[tid >> 6] = mx;
    __syncthreads();
    if (tid == 0)
        outp[b * 256 + o] = fmaxf(fmaxf(red[0], red[1]), fmaxf(red[2], red[3]));
}

extern "C" void kernel_launch(void* const* d_in, const int* in_sizes, int n_in,
                              void* d_out, int out_size, void* d_ws, size_t ws_size,
                              hipStream_t stream) {
    const float* x     = (const float*)d_in[0];
    const float* Wg    = (const float*)d_in[1];
    const float* bg    = (const float*)d_in[2];
    const float* Wt    = (const float*)d_in[3];
    const float* bt    = (const float*)d_in[4];
    const float* Wp    = (const float*)d_in[5];
    const float* bp    = (const float*)d_in[6];
    const float* Ww    = (const float*)d_in[7];
    const float* bw    = (const float*)d_in[8];
    const float* gamma = (const float*)d_in[9];
    const float* beta  = (const float*)d_in[10];
    float* outp = (float*)d_out;

    char* ws = (char*)d_ws;
    size_t off = 0;
    auto alloc = [&](size_t bytes) -> void* {
        void* p = ws + off;
        off = (off + bytes + 255) & ~(size_t)255;
        return p;
    };
    short* W_all = (short*)alloc((size_t)384 * 256 * 2);
    short* Ww16  = (short*)alloc((size_t)256 * 128 * 2);
    float* b_all = (float*)alloc((size_t)384 * 4);
    short* Out   = (short*)alloc((size_t)8 * 4096 * 384 * 2);
    short* Kmat  = (short*)alloc((size_t)8 * 1024 * 128 * 2);
    short* Vmat  = (short*)alloc((size_t)8 * 128 * 1024 * 2);
    short* Ybuf  = (short*)alloc((size_t)8 * 4096 * 128 * 2);
    short* wy    = (short*)alloc((size_t)8 * 256 * 4096 * 2);
    float* stats = (float*)alloc((size_t)256 * 2 * 4);
    float* ms    = (float*)alloc((size_t)256 * 2 * 4);

    hipMemsetAsync(stats, 0, 256 * 2 * 4, stream);

    k0_prep<<<512, 256, 0, stream>>>(Wg, Wt, Wp, bg, bt, bp, Ww, W_all, Ww16, b_all);
    k1_conv<<<dim3(32, 3, 8), 256, 0, stream>>>(x, W_all, b_all, Out);
    k2a_poolK<<<512, 256, 0, stream>>>(Out, Kmat);
    k2b_poolV<<<256, 256, 0, stream>>>(Out, Vmat);
    k3_attn<<<512, 256, 0, stream>>>(Out, Kmat, Vmat, Ybuf);
    k4_wy<<<dim3(16, 4, 8), 256, 0, stream>>>(Ww16, Ybuf, bw, wy, stats);
    k4b_stats<<<1, 256, 0, stream>>>(stats, ms);
    k5_bnmax<<<2048, 256, 0, stream>>>(wy, x, ms, gamma, beta, outp);
}

// Round 7
// 111.394 us; speedup vs baseline: 1.2690x; 1.0256x over previous
//
#include <hip/hip_runtime.h>
#include <hip/hip_bf16.h>
#include <stdint.h>

using f32x4  = __attribute__((ext_vector_type(4))) float;
using bf16x8 = __attribute__((ext_vector_type(8))) short;
using short4v = __attribute__((ext_vector_type(4))) short;

#define DEVINL static __device__ __forceinline__

DEVINL short f2bf(float f) {
    union { float f; uint32_t u; } v; v.f = f;
    uint32_t r = (v.u + 0x7FFFu + ((v.u >> 16) & 1u)) >> 16;   // RNE
    return (short)(uint16_t)r;
}
DEVINL float bf2f(short s) {
    union { uint32_t u; float f; } v; v.u = ((uint32_t)(uint16_t)s) << 16;
    return v.f;
}
DEVINL float fexp2(float x) {            // raw v_exp_f32 (2^x)
    float r;
    asm("v_exp_f32 %0, %1" : "=v"(r) : "v"(x));
    return r;
}

// async global -> LDS, 16B per lane. LDS dest is wave-uniform base + lane*16 (HW).
DEVINL void gld16(const short* g, short* l) {
    __builtin_amdgcn_global_load_lds(
        (const __attribute__((address_space(1))) unsigned int*)g,
        (__attribute__((address_space(3))) unsigned int*)l, 16, 0, 0);
}

#define LOG2E 1.44269504f

// ---------------- K0: weight prep (fp32 -> bf16, stack Wg|Wt|Wp) + stats zero ----------
// Wt/bt pre-scaled by log2e so attention logits are in base-2 domain.
__global__ __launch_bounds__(256) void k0_prep(
        const float* __restrict__ Wg, const float* __restrict__ Wt, const float* __restrict__ Wp,
        const float* __restrict__ bg, const float* __restrict__ bt, const float* __restrict__ bp,
        const float* __restrict__ Ww,
        short* __restrict__ W_all, short* __restrict__ Ww16, float* __restrict__ b_all,
        float* __restrict__ stats) {
    int i = blockIdx.x * 256 + threadIdx.x;
    if (blockIdx.x == 0) {
        stats[threadIdx.x] = 0.f;
        stats[threadIdx.x + 256] = 0.f;
    }
    if (i < 384 * 256) {
        int r = i >> 8, c = i & 255;
        float v = (r < 128) ? Wg[r * 256 + c]
                : (r < 256) ? Wt[(r - 128) * 256 + c] * LOG2E
                            : Wp[(r - 256) * 256 + c];
        W_all[i] = f2bf(v);
    } else if (i < 384 * 256 + 256 * 128) {
        int j = i - 384 * 256;
        Ww16[j] = f2bf(Ww[j]);
    }
    if (i < 384) {
        b_all[i] = (i < 128) ? bg[i] : (i < 256) ? bt[i - 128] * LOG2E : bp[i - 256];
    }
}

// ---------------- K1: fused conv1x1 x3 GEMM (conflict-free LDS, vector epilogue) ----
// Out[b][n][o] (o in [0,384): 0..127=g, 128..255=theta(log2e-scaled), 256..383=phi), bf16
__global__ __launch_bounds__(256) void k1_conv(const float* __restrict__ x,
        const short* __restrict__ W_all, const float* __restrict__ b_all,
        short* __restrict__ Out) {
    __shared__ short xs[128 * 32];       // [n][c], 16B-chunk XOR swizzle: ch ^= (n>>1)&3
    __shared__ short obuf[128 * 128];    // [n][o], 16B-chunk XOR swizzle: ch ^= n&15
    const int ntile = blockIdx.x;           // 32
    const int otile = blockIdx.y;           // 3
    const int b     = blockIdx.z;           // 8
    const int tid  = threadIdx.x;
    const int lane = tid & 63;
    const int wave = tid >> 6;
    const int wn = wave >> 1, wo = wave & 1;
    const int l15 = lane & 15, lh = lane >> 4;

    f32x4 acc[4][4];
    #pragma unroll
    for (int i = 0; i < 4; i++)
        #pragma unroll
        for (int j = 0; j < 4; j++) acc[i][j] = f32x4{0.f, 0.f, 0.f, 0.f};

    const int n0 = ntile * 128;
    const int ob = otile * 128 + wo * 64;
    const float* xb = x + (size_t)b * 256 * 4096;

    const int srow_base = (lane & 15) + wave * 16;    // + p*64
    const int sc0 = (lane >> 4) * 8;                  // channel chunk base

    for (int kt = 0; kt < 8; kt++) {
        __syncthreads();
        #pragma unroll
        for (int p = 0; p < 2; p++) {
            int row = srow_base + p * 64;
            const float* xp = xb + (size_t)(kt * 32 + sc0) * 4096 + n0 + row;
            bf16x8 w8;
            #pragma unroll
            for (int j = 0; j < 8; j++) w8[j] = f2bf(xp[(size_t)j * 4096]);
            int ch = (sc0 >> 3) ^ ((row >> 1) & 3);
            *(bf16x8*)&xs[row * 32 + ch * 8] = w8;
        }
        __syncthreads();

        bf16x8 a[4], w[4];
        #pragma unroll
        for (int nf = 0; nf < 4; nf++) {
            int row = wn * 64 + nf * 16 + l15;
            int ch  = lh ^ ((row >> 1) & 3);
            a[nf] = *(const bf16x8*)&xs[row * 32 + ch * 8];
        }
        #pragma unroll
        for (int of = 0; of < 4; of++)
            w[of] = *(const bf16x8*)(W_all + (size_t)(ob + of * 16 + l15) * 256 + kt * 32 + lh * 8);
        #pragma unroll
        for (int nf = 0; nf < 4; nf++)
            #pragma unroll
            for (int of = 0; of < 4; of++)
                acc[nf][of] = __builtin_amdgcn_mfma_f32_16x16x32_bf16(a[nf], w[of], acc[nf][of], 0, 0, 0);
    }

    #pragma unroll
    for (int of = 0; of < 4; of++) {
        int ocol = wo * 64 + of * 16 + l15;
        float bias = b_all[otile * 128 + ocol];
        #pragma unroll
        for (int nf = 0; nf < 4; nf++)
            #pragma unroll
            for (int r = 0; r < 4; r++) {
                int n  = wn * 64 + nf * 16 + lh * 4 + r;
                int ch = (ocol >> 3) ^ (n & 15);
                obuf[n * 128 + ch * 8 + (ocol & 7)] = f2bf(acc[nf][of][r] + bias);
            }
    }
    __syncthreads();
    #pragma unroll
    for (int p = 0; p < 8; p++) {
        int n  = wave * 4 + lh + p * 16;
        int ch = l15 ^ (n & 15);
        bf16x8 v = *(const bf16x8*)&obuf[n * 128 + ch * 8];
        *(bf16x8*)(Out + ((size_t)b * 4096 + n0 + n) * 384 + otile * 128 + l15 * 8) = v;
    }
}

// ---------------- K2a: maxpool phi -> Kmat[b][m][c] (bf16) ----------------
__global__ __launch_bounds__(256) void k2a_poolK(const short* __restrict__ Out, short* __restrict__ Kmat) {
    int t = blockIdx.x * 256 + threadIdx.x;
    int c8 = t & 15;
    int m  = (t >> 4) & 1023;
    int b  = t >> 14;
    int hp = m >> 5, wp = m & 31;
    int n0 = hp * 128 + wp * 2;
    const short* base = Out + (size_t)b * 4096 * 384 + 256 + c8 * 8;
    bf16x8 v0 = *(const bf16x8*)(base + (size_t)(n0) * 384);
    bf16x8 v1 = *(const bf16x8*)(base + (size_t)(n0 + 1) * 384);
    bf16x8 v2 = *(const bf16x8*)(base + (size_t)(n0 + 64) * 384);
    bf16x8 v3 = *(const bf16x8*)(base + (size_t)(n0 + 65) * 384);
    bf16x8 vo;
    #pragma unroll
    for (int i = 0; i < 8; i++) {
        float mx = fmaxf(fmaxf(bf2f(v0[i]), bf2f(v1[i])), fmaxf(bf2f(v2[i]), bf2f(v3[i])));
        vo[i] = f2bf(mx);
    }
    *(bf16x8*)(Kmat + ((size_t)b * 1024 + m) * 128 + c8 * 8) = vo;
}

// ---------------- K2b: maxpool g -> Vmat[b][c][m] (bf16, transposed) ----------------
__global__ __launch_bounds__(256) void k2b_poolV(const short* __restrict__ Out, short* __restrict__ Vmat) {
    __shared__ short g[128 * 136];
    int b  = blockIdx.x >> 5;
    int hp = blockIdx.x & 31;
    int tid = threadIdx.x;
    {
        int nloc = tid >> 1;
        int ch0  = (tid & 1) * 8;
        const short* src = Out + ((size_t)b * 4096 + hp * 128 + nloc) * 384;
        #pragma unroll
        for (int i = 0; i < 8; i++) {
            int chunk = ch0 + i;
            *(bf16x8*)&g[nloc * 136 + chunk * 8] = *(const bf16x8*)(src + chunk * 8);
        }
    }
    __syncthreads();
    int wp = tid & 31;
    int cb = tid >> 5;
    #pragma unroll
    for (int pass = 0; pass < 16; pass++) {
        int c = pass * 8 + cb;
        float a0 = bf2f(g[(2 * wp) * 136 + c]);
        float a1 = bf2f(g[(2 * wp + 1) * 136 + c]);
        float a2 = bf2f(g[(64 + 2 * wp) * 136 + c]);
        float a3 = bf2f(g[(65 + 2 * wp) * 136 + c]);
        float mx = fmaxf(fmaxf(a0, a1), fmaxf(a2, a3));
        Vmat[((size_t)b * 128 + c) * 1024 + hp * 32 + wp] = f2bf(mx);
    }
}

// ---------------- K3: flash attention (base-2 logits) ----------------
// 4 waves x 16 rows, 512 blocks, dbuf gld16 staging, counted-vmcnt raw barriers,
// swapped QK^T (lane-local softmax), defer-max, raw v_exp_f32.
__global__ __launch_bounds__(256) void k3_attn(const short* __restrict__ Out,
        const short* __restrict__ Kmat, const short* __restrict__ Vmat,
        short* __restrict__ Ybuf) {
    __shared__ short sK[2][64 * 128];   // [m][c], chunk-XOR-swizzled content
    __shared__ short sV[2][128 * 64];   // [c][m], chunk-XOR-swizzled content
    __shared__ short sP[4][16 * 64];    // per-wave P (A-layout, 8B-subchunk swizzle)

    const int bid = blockIdx.x;         // 512
    const int b   = bid & 7;
    const int nt  = bid >> 3;           // 64 tiles of 64 rows
    const int tid = threadIdx.x;
    const int lane = tid & 63;
    const int wave = tid >> 6;
    const int l15 = lane & 15, lh = lane >> 4;
    const int n0 = nt * 64 + wave * 16;

    const short* Kb = Kmat + (size_t)b * 1024 * 128;
    const short* Vb = Vmat + (size_t)b * 128 * 1024;
    short* sPw = sP[wave];

    auto STAGE = [&](int t, int bufi) {
        const int m0 = t * 64;
        #pragma unroll
        for (int i = 0; i < 4; i++) {
            const int segb = (i * 4 + wave) * 64;          // wave-uniform, chunk units
            const int rowK = (segb >> 4) + (lane >> 4);
            const int chkK = lane & 15;
            gld16(Kb + (size_t)(m0 + rowK) * 128 + ((chkK ^ (rowK & 15)) << 3),
                  &sK[bufi][segb * 8]);
            const int rowV = (segb >> 3) + (lane >> 3);
            const int chkV = lane & 7;
            gld16(Vb + (size_t)rowV * 1024 + m0 + ((chkV ^ (rowV & 7)) << 3),
                  &sV[bufi][segb * 8]);
        }
    };

    bf16x8 q[4];
    {
        const short* qrow = Out + ((size_t)b * 4096 + n0 + l15) * 384 + 128;
        #pragma unroll
        for (int ks = 0; ks < 4; ks++)
            q[ks] = *(const bf16x8*)(qrow + ks * 32 + lh * 8);
    }

    f32x4 y[8];
    #pragma unroll
    for (int cf = 0; cf < 8; cf++) y[cf] = f32x4{0.f, 0.f, 0.f, 0.f};
    float mrun = -1e30f, lrun = 0.f;    // per-lane: q-row = l15 (replicated over lh); base-2 domain

    STAGE(0, 0);
    int cur = 0;

    for (int t = 0; t < 16; t++) {
        if (t < 15) {
            STAGE(t + 1, cur ^ 1);
            asm volatile("s_waitcnt vmcnt(8)" ::: "memory");
        } else {
            asm volatile("s_waitcnt vmcnt(0)" ::: "memory");
        }
        __builtin_amdgcn_s_barrier();
        __builtin_amdgcn_sched_barrier(0);

        const short* cK = sK[cur];
        const short* cV = sV[cur];

        // S^T = K Q^T : lane holds q-row = l15, m = mf*16 + lh*4 + r (logits in log2 units)
        f32x4 S[4];
        #pragma unroll
        for (int mf = 0; mf < 4; mf++) S[mf] = f32x4{0.f, 0.f, 0.f, 0.f};
        #pragma unroll
        for (int ks = 0; ks < 4; ks++) {
            bf16x8 kf[4];
            #pragma unroll
            for (int mf = 0; mf < 4; mf++) {
                int mrow = mf * 16 + l15;
                int jj   = ks * 4 + lh;
                kf[mf] = *(const bf16x8*)&cK[mrow * 128 + ((jj ^ (mrow & 15)) << 3)];
            }
            __builtin_amdgcn_s_setprio(1);
            #pragma unroll
            for (int mf = 0; mf < 4; mf++)
                S[mf] = __builtin_amdgcn_mfma_f32_16x16x32_bf16(kf[mf], q[ks], S[mf], 0, 0, 0);
            __builtin_amdgcn_s_setprio(0);
        }

        // lane-local softmax (base 2)
        float pm = S[0][0];
        #pragma unroll
        for (int mf = 0; mf < 4; mf++)
            #pragma unroll
            for (int r = 0; r < 4; r++) pm = fmaxf(pm, S[mf][r]);
        pm = fmaxf(pm, __shfl_xor(pm, 16));
        pm = fmaxf(pm, __shfl_xor(pm, 32));

        if (__any(pm > mrun + 8.656f)) {       // defer-max (6 nats in log2 units)
            float mnew  = fmaxf(mrun, pm);
            float alpha = fexp2(mrun - mnew);
            mrun = mnew;
            lrun *= alpha;
            float aR[4];
            #pragma unroll
            for (int r = 0; r < 4; r++) aR[r] = __shfl(alpha, lh * 4 + r);
            #pragma unroll
            for (int cf = 0; cf < 8; cf++)
                #pragma unroll
                for (int r = 0; r < 4; r++) y[cf][r] *= aR[r];
        }
        float rs = 0.f;
        #pragma unroll
        for (int mf = 0; mf < 4; mf++)
            #pragma unroll
            for (int r = 0; r < 4; r++) {
                float p = fexp2(S[mf][r] - mrun);
                S[mf][r] = p;
                rs += p;
            }
        rs += __shfl_xor(rs, 16);
        rs += __shfl_xor(rs, 32);
        lrun += rs;

        // P -> per-wave LDS, vectorized 8B writes, 8B-subchunk XOR swizzle
        #pragma unroll
        for (int mf = 0; mf < 4; mf++) {
            short4v pk = { f2bf(S[mf][0]), f2bf(S[mf][1]), f2bf(S[mf][2]), f2bf(S[mf][3]) };
            *(short4v*)&sPw[(l15 << 6) + (((mf * 4 + lh) ^ l15) << 2)] = pk;
        }

        // y += P @ V^T
        #pragma unroll
        for (int ks2 = 0; ks2 < 2; ks2++) {
            int u0 = ks2 * 8 + lh * 2;
            short4v lo = *(const short4v*)&sPw[(l15 << 6) + (((u0)     ^ l15) << 2)];
            short4v hi = *(const short4v*)&sPw[(l15 << 6) + (((u0 + 1) ^ l15) << 2)];
            bf16x8 pa = { lo.x, lo.y, lo.z, lo.w, hi.x, hi.y, hi.z, hi.w };
            int jj = ks2 * 4 + lh;
            __builtin_amdgcn_s_setprio(1);
            #pragma unroll
            for (int cf = 0; cf < 8; cf++) {
                int crow = cf * 16 + l15;
                bf16x8 vf = *(const bf16x8*)&cV[crow * 64 + ((jj ^ (crow & 7)) << 3)];
                y[cf] = __builtin_amdgcn_mfma_f32_16x16x32_bf16(pa, vf, y[cf], 0, 0, 0);
            }
            __builtin_amdgcn_s_setprio(0);
        }

        __builtin_amdgcn_sched_barrier(0);
        __builtin_amdgcn_s_barrier();       // protect buf[cur] from next-iter overwrite
        cur ^= 1;
    }

    // epilogue
    float linv[4];
    #pragma unroll
    for (int r = 0; r < 4; r++) linv[r] = 1.f / __shfl(lrun, lh * 4 + r);
    #pragma unroll
    for (int cf = 0; cf < 8; cf++) {
        int c = cf * 16 + l15;
        #pragma unroll
        for (int r = 0; r < 4; r++)
            Ybuf[((size_t)b * 4096 + n0 + lh * 4 + r) * 128 + c] = f2bf(y[cf][r] * linv[r]);
    }
}

// ---------------- K4: wy = Ww @ y^T (+bias) + BN partial stats ----------------
__global__ __launch_bounds__(256) void k4_wy(const short* __restrict__ Ww16,
        const short* __restrict__ Ybuf, const float* __restrict__ bw,
        short* __restrict__ wy, float* __restrict__ stats) {
    __shared__ float sums[4][64][2];
    const int nt = blockIdx.x;     // 16
    const int ot = blockIdx.y;     // 4
    const int b  = blockIdx.z;
    const int tid = threadIdx.x;
    const int lane = tid & 63, wave = tid >> 6;
    const int l15 = lane & 15, lh = lane >> 4;
    const int ob = ot * 64;
    const int nb = nt * 256 + wave * 64;

    bf16x8 aw[4][4];
    #pragma unroll
    for (int of = 0; of < 4; of++)
        #pragma unroll
        for (int ks = 0; ks < 4; ks++)
            aw[of][ks] = *(const bf16x8*)(Ww16 + (size_t)(ob + of * 16 + l15) * 128 + ks * 32 + lh * 8);

    f32x4 acc[4][4];               // [of][nf]
    #pragma unroll
    for (int i = 0; i < 4; i++)
        #pragma unroll
        for (int j = 0; j < 4; j++) acc[i][j] = f32x4{0.f, 0.f, 0.f, 0.f};

    #pragma unroll
    for (int nf = 0; nf < 4; nf++) {
        bf16x8 by[4];
        #pragma unroll
        for (int ks = 0; ks < 4; ks++)
            by[ks] = *(const bf16x8*)(Ybuf + ((size_t)b * 4096 + nb + nf * 16 + l15) * 128 + ks * 32 + lh * 8);
        #pragma unroll
        for (int of = 0; of < 4; of++)
            #pragma unroll
            for (int ks = 0; ks < 4; ks++)
                acc[of][nf] = __builtin_amdgcn_mfma_f32_16x16x32_bf16(aw[of][ks], by[ks], acc[of][nf], 0, 0, 0);
    }

    #pragma unroll
    for (int of = 0; of < 4; of++) {
        #pragma unroll
        for (int r = 0; r < 4; r++) {
            int o = ob + of * 16 + lh * 4 + r;
            float bias = bw[o];
            float s = 0.f, s2 = 0.f;
            #pragma unroll
            for (int nf = 0; nf < 4; nf++) {
                float v = acc[of][nf][r] + bias;
                wy[((size_t)b * 256 + o) * 4096 + nb + nf * 16 + l15] = f2bf(v);
                s += v; s2 += v * v;
            }
            #pragma unroll
            for (int off = 1; off < 16; off <<= 1) { s += __shfl_xor(s, off); s2 += __shfl_xor(s2, off); }
            if (l15 == 0) {
                sums[wave][of * 16 + lh * 4 + r][0] = s;
                sums[wave][of * 16 + lh * 4 + r][1] = s2;
            }
        }
    }
    __syncthreads();
    if (tid < 64) {
        float s  = sums[0][tid][0] + sums[1][tid][0] + sums[2][tid][0] + sums[3][tid][0];
        float s2 = sums[0][tid][1] + sums[1][tid][1] + sums[2][tid][1] + sums[3][tid][1];
        atomicAdd(&stats[(ob + tid) * 2], s);
        atomicAdd(&stats[(ob + tid) * 2 + 1], s2);
    }
}

// ---------------- K4b: finalize mean / rstd ----------------
__global__ __launch_bounds__(256) void k4b_stats(const float* __restrict__ stats, float* __restrict__ ms) {
    int o = threadIdx.x;
    float mean = stats[o * 2] * (1.f / 32768.f);
    float var  = stats[o * 2 + 1] * (1.f / 32768.f) - mean * mean;
    ms[o * 2] = mean;
    ms[o * 2 + 1] = rsqrtf(var + 1e-5f);
}

// ---------------- K5: BN apply + residual + global spatial max ----------------
__global__ __launch_bounds__(256) void k5_bnmax(const short* __restrict__ wy,
        const float* __restrict__ x, const float* __restrict__ ms,
        const float* __restrict__ gamma, const float* __restrict__ beta,
        float* __restrict__ outp) {
    int b = blockIdx.x >> 8;
    int o = blockIdx.x & 255;
    int tid = threadIdx.x;
    float mean = ms[o * 2], rstd = ms[o * 2 + 1];
    float A = rstd * gamma[o];
    float B = beta[o] - mean * A;
    const short* pw = wy + ((size_t)b * 256 + o) * 4096;
    const float* px = x + ((size_t)b * 256 + o) * 4096;
    float mx = -1e30f;
    #pragma unroll
    for (int j = 0; j < 2; j++) {
        int e = (tid + j * 256) * 8;
        bf16x8 w8 = *(const bf16x8*)(pw + e);
        float4 xa = *(const float4*)(px + e);
        float4 xb = *(const float4*)(px + e + 4);
        mx = fmaxf(mx, bf2f(w8[0]) * A + B + xa.x);
        mx = fmaxf(mx, bf2f(w8[1]) * A + B + xa.y);
        mx = fmaxf(mx, bf2f(w8[2]) * A + B + xa.z);
        mx = fmaxf(mx, bf2f(w8[3]) * A + B + xa.w);
        mx = fmaxf(mx, bf2f(w8[4]) * A + B + xb.x);
        mx = fmaxf(mx, bf2f(w8[5]) * A + B + xb.y);
        mx = fmaxf(mx, bf2f(w8[6]) * A + B + xb.z);
        mx = fmaxf(mx, bf2f(w8[7]) * A + B + xb.w);
    }
    #pragma unroll
    for (int off = 1; off < 64; off <<= 1) mx = fmaxf(mx, __shfl_xor(mx, off));
    __shared__ float red[4];
    if ((tid & 63) == 0) red[tid >> 6] = mx;
    __syncthreads();
    if (tid == 0)
        outp[b * 256 + o] = fmaxf(fmaxf(red[0], red[1]), fmaxf(red[2], red[3]));
}

extern "C" void kernel_launch(void* const* d_in, const int* in_sizes, int n_in,
                              void* d_out, int out_size, void* d_ws, size_t ws_size,
                              hipStream_t stream) {
    const float* x     = (const float*)d_in[0];
    const float* Wg    = (const float*)d_in[1];
    const float* bg    = (const float*)d_in[2];
    const float* Wt    = (const float*)d_in[3];
    const float* bt    = (const float*)d_in[4];
    const float* Wp    = (const float*)d_in[5];
    const float* bp    = (const float*)d_in[6];
    const float* Ww    = (const float*)d_in[7];
    const float* bw    = (const float*)d_in[8];
    const float* gamma = (const float*)d_in[9];
    const float* beta  = (const float*)d_in[10];
    float* outp = (float*)d_out;

    char* ws = (char*)d_ws;
    size_t off = 0;
    auto alloc = [&](size_t bytes) -> void* {
        void* p = ws + off;
        off = (off + bytes + 255) & ~(size_t)255;
        return p;
    };
    short* W_all = (short*)alloc((size_t)384 * 256 * 2);
    short* Ww16  = (short*)alloc((size_t)256 * 128 * 2);
    float* b_all = (float*)alloc((size_t)384 * 4);
    short* Out   = (short*)alloc((size_t)8 * 4096 * 384 * 2);
    short* Kmat  = (short*)alloc((size_t)8 * 1024 * 128 * 2);
    short* Vmat  = (short*)alloc((size_t)8 * 128 * 1024 * 2);
    short* Ybuf  = (short*)alloc((size_t)8 * 4096 * 128 * 2);
    short* wy    = (short*)alloc((size_t)8 * 256 * 4096 * 2);
    float* stats = (float*)alloc((size_t)256 * 2 * 4);
    float* ms    = (float*)alloc((size_t)256 * 2 * 4);

    k0_prep<<<512, 256, 0, stream>>>(Wg, Wt, Wp, bg, bt, bp, Ww, W_all, Ww16, b_all, stats);
    k1_conv<<<dim3(32, 3, 8), 256, 0, stream>>>(x, W_all, b_all, Out);
    k2a_poolK<<<512, 256, 0, stream>>>(Out, Kmat);
    k2b_poolV<<<256, 256, 0, stream>>>(Out, Vmat);
    k3_attn<<<512, 256, 0, stream>>>(Out, Kmat, Vmat, Ybuf);
    k4_wy<<<dim3(16, 4, 8), 256, 0, stream>>>(Ww16, Ybuf, bw, wy, stats);
    k4b_stats<<<1, 256, 0, stream>>>(stats, ms);
    k5_bnmax<<<2048, 256, 0, stream>>>(wy, x, ms, gamma, beta, outp);
}

// Round 8
// 100.177 us; speedup vs baseline: 1.4111x; 1.1120x over previous
//
#include <hip/hip_runtime.h>
#include <hip/hip_bf16.h>
#include <stdint.h>

using f32x4  = __attribute__((ext_vector_type(4))) float;
using bf16x8 = __attribute__((ext_vector_type(8))) short;
using short4v = __attribute__((ext_vector_type(4))) short;

#define DEVINL static __device__ __forceinline__

DEVINL short f2bf(float f) {
    union { float f; uint32_t u; } v; v.f = f;
    uint32_t r = (v.u + 0x7FFFu + ((v.u >> 16) & 1u)) >> 16;   // RNE
    return (short)(uint16_t)r;
}
DEVINL float bf2f(short s) {
    union { uint32_t u; float f; } v; v.u = ((uint32_t)(uint16_t)s) << 16;
    return v.f;
}
DEVINL float fexp2(float x) {            // raw v_exp_f32 (2^x)
    float r;
    asm("v_exp_f32 %0, %1" : "=v"(r) : "v"(x));
    return r;
}

// async global -> LDS, 16B per lane. LDS dest is wave-uniform base + lane*16 (HW).
DEVINL void gld16(const short* g, short* l) {
    __builtin_amdgcn_global_load_lds(
        (const __attribute__((address_space(1))) unsigned int*)g,
        (__attribute__((address_space(3))) unsigned int*)l, 16, 0, 0);
}

#define LOG2E 1.44269504f

// ---------------- K0: weight prep (fp32 -> bf16, stack Wg|Wt|Wp) + stats zero ----------
__global__ __launch_bounds__(256) void k0_prep(
        const float* __restrict__ Wg, const float* __restrict__ Wt, const float* __restrict__ Wp,
        const float* __restrict__ bg, const float* __restrict__ bt, const float* __restrict__ bp,
        const float* __restrict__ Ww,
        short* __restrict__ W_all, short* __restrict__ Ww16, float* __restrict__ b_all,
        float* __restrict__ stats) {
    int i = blockIdx.x * 256 + threadIdx.x;
    if (blockIdx.x == 0) {
        stats[threadIdx.x] = 0.f;
        stats[threadIdx.x + 256] = 0.f;
    }
    if (i < 384 * 256) {
        int r = i >> 8, c = i & 255;
        float v = (r < 128) ? Wg[r * 256 + c]
                : (r < 256) ? Wt[(r - 128) * 256 + c] * LOG2E
                            : Wp[(r - 256) * 256 + c];
        W_all[i] = f2bf(v);
    } else if (i < 384 * 256 + 256 * 128) {
        int j = i - 384 * 256;
        Ww16[j] = f2bf(Ww[j]);
    }
    if (i < 384) {
        b_all[i] = (i < 128) ? bg[i] : (i < 256) ? bt[i - 128] * LOG2E : bp[i - 256];
    }
}

// ---------------- K1: fused conv1x1 x3 GEMM + fused 2x2 maxpool epilogues ----------
// otile 0 (g)    -> pooled, transposed into Vmat[b][c][m]
// otile 1 (theta)-> OutT[b][n][128] (log2e-scaled logits)
// otile 2 (phi)  -> pooled into Kmat[b][m][c]
// Each block's 128-n tile covers image rows 2*ntile, 2*ntile+1 => pool row ntile.
__global__ __launch_bounds__(256) void k1_conv(const float* __restrict__ x,
        const short* __restrict__ W_all, const float* __restrict__ b_all,
        short* __restrict__ OutT, short* __restrict__ Kmat, short* __restrict__ Vmat) {
    __shared__ short xs[128 * 32];       // [n][c], 16B-chunk XOR swizzle: ch ^= (n>>1)&3
    __shared__ short obuf[128 * 128];    // [n][o], 16B-chunk XOR swizzle: ch ^= n&15
    const int ntile = blockIdx.x;           // 32
    const int otile = blockIdx.y;           // 3
    const int b     = blockIdx.z;           // 8
    const int tid  = threadIdx.x;
    const int lane = tid & 63;
    const int wave = tid >> 6;
    const int wn = wave >> 1, wo = wave & 1;
    const int l15 = lane & 15, lh = lane >> 4;

    f32x4 acc[4][4];
    #pragma unroll
    for (int i = 0; i < 4; i++)
        #pragma unroll
        for (int j = 0; j < 4; j++) acc[i][j] = f32x4{0.f, 0.f, 0.f, 0.f};

    const int n0 = ntile * 128;
    const int ob = otile * 128 + wo * 64;
    const float* xb = x + (size_t)b * 256 * 4096;

    const int srow_base = (lane & 15) + wave * 16;    // + p*64
    const int sc0 = (lane >> 4) * 8;                  // channel chunk base

    for (int kt = 0; kt < 8; kt++) {
        __syncthreads();
        #pragma unroll
        for (int p = 0; p < 2; p++) {
            int row = srow_base + p * 64;
            const float* xp = xb + (size_t)(kt * 32 + sc0) * 4096 + n0 + row;
            bf16x8 w8;
            #pragma unroll
            for (int j = 0; j < 8; j++) w8[j] = f2bf(xp[(size_t)j * 4096]);
            int ch = (sc0 >> 3) ^ ((row >> 1) & 3);
            *(bf16x8*)&xs[row * 32 + ch * 8] = w8;
        }
        __syncthreads();

        bf16x8 a[4], w[4];
        #pragma unroll
        for (int nf = 0; nf < 4; nf++) {
            int row = wn * 64 + nf * 16 + l15;
            int ch  = lh ^ ((row >> 1) & 3);
            a[nf] = *(const bf16x8*)&xs[row * 32 + ch * 8];
        }
        #pragma unroll
        for (int of = 0; of < 4; of++)
            w[of] = *(const bf16x8*)(W_all + (size_t)(ob + of * 16 + l15) * 256 + kt * 32 + lh * 8);
        #pragma unroll
        for (int nf = 0; nf < 4; nf++)
            #pragma unroll
            for (int of = 0; of < 4; of++)
                acc[nf][of] = __builtin_amdgcn_mfma_f32_16x16x32_bf16(a[nf], w[of], acc[nf][of], 0, 0, 0);
    }

    // write accumulators (+bias) into XOR-swizzled obuf
    #pragma unroll
    for (int of = 0; of < 4; of++) {
        int ocol = wo * 64 + of * 16 + l15;
        float bias = b_all[otile * 128 + ocol];
        #pragma unroll
        for (int nf = 0; nf < 4; nf++)
            #pragma unroll
            for (int r = 0; r < 4; r++) {
                int n  = wn * 64 + nf * 16 + lh * 4 + r;
                int ch = (ocol >> 3) ^ (n & 15);
                obuf[n * 128 + ch * 8 + (ocol & 7)] = f2bf(acc[nf][of][r] + bias);
            }
    }
    __syncthreads();

    if (otile == 1) {
        // theta: compact [n][128] output, b128 stores
        #pragma unroll
        for (int p = 0; p < 8; p++) {
            int n  = wave * 4 + lh + p * 16;
            int ch = l15 ^ (n & 15);
            bf16x8 v = *(const bf16x8*)&obuf[n * 128 + ch * 8];
            *(bf16x8*)(OutT + ((size_t)b * 4096 + n0 + n) * 128 + l15 * 8) = v;
        }
    } else if (otile == 2) {
        // phi: 2x2 maxpool -> Kmat[b][m][c], m = ntile*32 + wp
        const int wp = tid >> 3;
        const int cc = (tid & 7) * 16;
        short* kdst = Kmat + ((size_t)b * 1024 + ntile * 32 + wp) * 128 + cc;
        #pragma unroll
        for (int cblk = 0; cblk < 2; cblk++) {
            const int chunk = (cc >> 3) + cblk;
            float mx[8];
            #pragma unroll
            for (int j = 0; j < 8; j++) mx[j] = -1e30f;
            #pragma unroll
            for (int q4 = 0; q4 < 4; q4++) {
                int n = (q4 >> 1) * 64 + 2 * wp + (q4 & 1);
                bf16x8 v = *(const bf16x8*)&obuf[n * 128 + ((chunk ^ (n & 15)) * 8)];
                #pragma unroll
                for (int j = 0; j < 8; j++) mx[j] = fmaxf(mx[j], bf2f(v[j]));
            }
            bf16x8 vo;
            #pragma unroll
            for (int j = 0; j < 8; j++) vo[j] = f2bf(mx[j]);
            *(bf16x8*)(kdst + cblk * 8) = vo;
        }
    } else {
        // g: 2x2 maxpool + transpose -> Vmat[b][c][m]
        const int c   = tid >> 1;
        const int wp0 = (tid & 1) * 16;
        const int chb = c >> 3, cl = c & 7;
        #pragma unroll
        for (int half = 0; half < 2; half++) {
            bf16x8 vo;
            #pragma unroll
            for (int j = 0; j < 8; j++) {
                int wp = wp0 + half * 8 + j;
                float mx = -1e30f;
                #pragma unroll
                for (int q4 = 0; q4 < 4; q4++) {
                    int n = (q4 >> 1) * 64 + 2 * wp + (q4 & 1);
                    mx = fmaxf(mx, bf2f(obuf[n * 128 + ((chb ^ (n & 15)) * 8) + cl]));
                }
                vo[j] = f2bf(mx);
            }
            *(bf16x8*)(Vmat + ((size_t)b * 128 + c) * 1024 + ntile * 32 + wp0 + half * 8) = vo;
        }
    }
}

// ---------------- K3: flash attention (base-2 logits) ----------------
// 4 waves x 16 rows, 512 blocks, dbuf gld16 staging, counted-vmcnt raw barriers,
// swapped QK^T (lane-local softmax), defer-max, raw v_exp_f32.
__global__ __launch_bounds__(256) void k3_attn(const short* __restrict__ OutT,
        const short* __restrict__ Kmat, const short* __restrict__ Vmat,
        short* __restrict__ Ybuf) {
    __shared__ short sK[2][64 * 128];   // [m][c], chunk-XOR-swizzled content
    __shared__ short sV[2][128 * 64];   // [c][m], chunk-XOR-swizzled content
    __shared__ short sP[4][16 * 64];    // per-wave P (A-layout, 8B-subchunk swizzle)

    const int bid = blockIdx.x;         // 512
    const int b   = bid & 7;
    const int nt  = bid >> 3;           // 64 tiles of 64 rows
    const int tid = threadIdx.x;
    const int lane = tid & 63;
    const int wave = tid >> 6;
    const int l15 = lane & 15, lh = lane >> 4;
    const int n0 = nt * 64 + wave * 16;

    const short* Kb = Kmat + (size_t)b * 1024 * 128;
    const short* Vb = Vmat + (size_t)b * 128 * 1024;
    short* sPw = sP[wave];

    auto STAGE = [&](int t, int bufi) {
        const int m0 = t * 64;
        #pragma unroll
        for (int i = 0; i < 4; i++) {
            const int segb = (i * 4 + wave) * 64;          // wave-uniform, chunk units
            const int rowK = (segb >> 4) + (lane >> 4);
            const int chkK = lane & 15;
            gld16(Kb + (size_t)(m0 + rowK) * 128 + ((chkK ^ (rowK & 15)) << 3),
                  &sK[bufi][segb * 8]);
            const int rowV = (segb >> 3) + (lane >> 3);
            const int chkV = lane & 7;
            gld16(Vb + (size_t)rowV * 1024 + m0 + ((chkV ^ (rowV & 7)) << 3),
                  &sV[bufi][segb * 8]);
        }
    };

    bf16x8 q[4];
    {
        const short* qrow = OutT + ((size_t)b * 4096 + n0 + l15) * 128;
        #pragma unroll
        for (int ks = 0; ks < 4; ks++)
            q[ks] = *(const bf16x8*)(qrow + ks * 32 + lh * 8);
    }

    f32x4 y[8];
    #pragma unroll
    for (int cf = 0; cf < 8; cf++) y[cf] = f32x4{0.f, 0.f, 0.f, 0.f};
    float mrun = -1e30f, lrun = 0.f;    // per-lane: q-row = l15 (replicated over lh); base-2

    STAGE(0, 0);
    int cur = 0;

    for (int t = 0; t < 16; t++) {
        if (t < 15) {
            STAGE(t + 1, cur ^ 1);
            asm volatile("s_waitcnt vmcnt(8)" ::: "memory");
        } else {
            asm volatile("s_waitcnt vmcnt(0)" ::: "memory");
        }
        __builtin_amdgcn_s_barrier();
        __builtin_amdgcn_sched_barrier(0);

        const short* cK = sK[cur];
        const short* cV = sV[cur];

        f32x4 S[4];
        #pragma unroll
        for (int mf = 0; mf < 4; mf++) S[mf] = f32x4{0.f, 0.f, 0.f, 0.f};
        #pragma unroll
        for (int ks = 0; ks < 4; ks++) {
            bf16x8 kf[4];
            #pragma unroll
            for (int mf = 0; mf < 4; mf++) {
                int mrow = mf * 16 + l15;
                int jj   = ks * 4 + lh;
                kf[mf] = *(const bf16x8*)&cK[mrow * 128 + ((jj ^ (mrow & 15)) << 3)];
            }
            __builtin_amdgcn_s_setprio(1);
            #pragma unroll
            for (int mf = 0; mf < 4; mf++)
                S[mf] = __builtin_amdgcn_mfma_f32_16x16x32_bf16(kf[mf], q[ks], S[mf], 0, 0, 0);
            __builtin_amdgcn_s_setprio(0);
        }

        // lane-local softmax (base 2)
        float pm = S[0][0];
        #pragma unroll
        for (int mf = 0; mf < 4; mf++)
            #pragma unroll
            for (int r = 0; r < 4; r++) pm = fmaxf(pm, S[mf][r]);
        pm = fmaxf(pm, __shfl_xor(pm, 16));
        pm = fmaxf(pm, __shfl_xor(pm, 32));

        if (__any(pm > mrun + 8.656f)) {       // defer-max (6 nats in log2 units)
            float mnew  = fmaxf(mrun, pm);
            float alpha = fexp2(mrun - mnew);
            mrun = mnew;
            lrun *= alpha;
            float aR[4];
            #pragma unroll
            for (int r = 0; r < 4; r++) aR[r] = __shfl(alpha, lh * 4 + r);
            #pragma unroll
            for (int cf = 0; cf < 8; cf++)
                #pragma unroll
                for (int r = 0; r < 4; r++) y[cf][r] *= aR[r];
        }
        float rs = 0.f;
        #pragma unroll
        for (int mf = 0; mf < 4; mf++)
            #pragma unroll
            for (int r = 0; r < 4; r++) {
                float p = fexp2(S[mf][r] - mrun);
                S[mf][r] = p;
                rs += p;
            }
        rs += __shfl_xor(rs, 16);
        rs += __shfl_xor(rs, 32);
        lrun += rs;

        // P -> per-wave LDS, vectorized 8B writes, 8B-subchunk XOR swizzle
        #pragma unroll
        for (int mf = 0; mf < 4; mf++) {
            short4v pk = { f2bf(S[mf][0]), f2bf(S[mf][1]), f2bf(S[mf][2]), f2bf(S[mf][3]) };
            *(short4v*)&sPw[(l15 << 6) + (((mf * 4 + lh) ^ l15) << 2)] = pk;
        }

        // y += P @ V^T
        #pragma unroll
        for (int ks2 = 0; ks2 < 2; ks2++) {
            int u0 = ks2 * 8 + lh * 2;
            short4v lo = *(const short4v*)&sPw[(l15 << 6) + (((u0)     ^ l15) << 2)];
            short4v hi = *(const short4v*)&sPw[(l15 << 6) + (((u0 + 1) ^ l15) << 2)];
            bf16x8 pa = { lo.x, lo.y, lo.z, lo.w, hi.x, hi.y, hi.z, hi.w };
            int jj = ks2 * 4 + lh;
            __builtin_amdgcn_s_setprio(1);
            #pragma unroll
            for (int cf = 0; cf < 8; cf++) {
                int crow = cf * 16 + l15;
                bf16x8 vf = *(const bf16x8*)&cV[crow * 64 + ((jj ^ (crow & 7)) << 3)];
                y[cf] = __builtin_amdgcn_mfma_f32_16x16x32_bf16(pa, vf, y[cf], 0, 0, 0);
            }
            __builtin_amdgcn_s_setprio(0);
        }

        __builtin_amdgcn_sched_barrier(0);
        __builtin_amdgcn_s_barrier();       // protect buf[cur] from next-iter overwrite
        cur ^= 1;
    }

    // epilogue
    float linv[4];
    #pragma unroll
    for (int r = 0; r < 4; r++) linv[r] = 1.f / __shfl(lrun, lh * 4 + r);
    #pragma unroll
    for (int cf = 0; cf < 8; cf++) {
        int c = cf * 16 + l15;
        #pragma unroll
        for (int r = 0; r < 4; r++)
            Ybuf[((size_t)b * 4096 + n0 + lh * 4 + r) * 128 + c] = f2bf(y[cf][r] * linv[r]);
    }
}

// ---------------- K4: wy = Ww @ y^T (+bias) + BN partial stats ----------------
__global__ __launch_bounds__(256) void k4_wy(const short* __restrict__ Ww16,
        const short* __restrict__ Ybuf, const float* __restrict__ bw,
        short* __restrict__ wy, float* __restrict__ stats) {
    __shared__ float sums[4][64][2];
    const int nt = blockIdx.x;     // 16
    const int ot = blockIdx.y;     // 4
    const int b  = blockIdx.z;
    const int tid = threadIdx.x;
    const int lane = tid & 63, wave = tid >> 6;
    const int l15 = lane & 15, lh = lane >> 4;
    const int ob = ot * 64;
    const int nb = nt * 256 + wave * 64;

    bf16x8 aw[4][4];
    #pragma unroll
    for (int of = 0; of < 4; of++)
        #pragma unroll
        for (int ks = 0; ks < 4; ks++)
            aw[of][ks] = *(const bf16x8*)(Ww16 + (size_t)(ob + of * 16 + l15) * 128 + ks * 32 + lh * 8);

    f32x4 acc[4][4];               // [of][nf]
    #pragma unroll
    for (int i = 0; i < 4; i++)
        #pragma unroll
        for (int j = 0; j < 4; j++) acc[i][j] = f32x4{0.f, 0.f, 0.f, 0.f};

    #pragma unroll
    for (int nf = 0; nf < 4; nf++) {
        bf16x8 by[4];
        #pragma unroll
        for (int ks = 0; ks < 4; ks++)
            by[ks] = *(const bf16x8*)(Ybuf + ((size_t)b * 4096 + nb + nf * 16 + l15) * 128 + ks * 32 + lh * 8);
        #pragma unroll
        for (int of = 0; of < 4; of++)
            #pragma unroll
            for (int ks = 0; ks < 4; ks++)
                acc[of][nf] = __builtin_amdgcn_mfma_f32_16x16x32_bf16(aw[of][ks], by[ks], acc[of][nf], 0, 0, 0);
    }

    #pragma unroll
    for (int of = 0; of < 4; of++) {
        #pragma unroll
        for (int r = 0; r < 4; r++) {
            int o = ob + of * 16 + lh * 4 + r;
            float bias = bw[o];
            float s = 0.f, s2 = 0.f;
            #pragma unroll
            for (int nf = 0; nf < 4; nf++) {
                float v = acc[of][nf][r] + bias;
                wy[((size_t)b * 256 + o) * 4096 + nb + nf * 16 + l15] = f2bf(v);
                s += v; s2 += v * v;
            }
            #pragma unroll
            for (int off = 1; off < 16; off <<= 1) { s += __shfl_xor(s, off); s2 += __shfl_xor(s2, off); }
            if (l15 == 0) {
                sums[wave][of * 16 + lh * 4 + r][0] = s;
                sums[wave][of * 16 + lh * 4 + r][1] = s2;
            }
        }
    }
    __syncthreads();
    if (tid < 64) {
        float s  = sums[0][tid][0] + sums[1][tid][0] + sums[2][tid][0] + sums[3][tid][0];
        float s2 = sums[0][tid][1] + sums[1][tid][1] + sums[2][tid][1] + sums[3][tid][1];
        atomicAdd(&stats[(ob + tid) * 2], s);
        atomicAdd(&stats[(ob + tid) * 2 + 1], s2);
    }
}

// ---------------- K5: BN finalize + apply + residual + global spatial max ----------------
__global__ __launch_bounds__(256) void k5_bnmax(const short* __restrict__ wy,
        const float* __restrict__ x, const float* __restrict__ stats,
        const float* __restrict__ gamma, const float* __restrict__ beta,
        float* __restrict__ outp) {
    int b = blockIdx.x >> 8;
    int o = blockIdx.x & 255;
    int tid = threadIdx.x;
    float mean = stats[o * 2] * (1.f / 32768.f);
    float var  = stats[o * 2 + 1] * (1.f / 32768.f) - mean * mean;
    float rstd = rsqrtf(var + 1e-5f);
    float A = rstd * gamma[o];
    float B = beta[o] - mean * A;
    const short* pw = wy + ((size_t)b * 256 + o) * 4096;
    const float* px = x + ((size_t)b * 256 + o) * 4096;
    float mx = -1e30f;
    #pragma unroll
    for (int j = 0; j < 2; j++) {
        int e = (tid + j * 256) * 8;
        bf16x8 w8 = *(const bf16x8*)(pw + e);
        float4 xa = *(const float4*)(px + e);
        float4 xb = *(const float4*)(px + e + 4);
        mx = fmaxf(mx, bf2f(w8[0]) * A + B + xa.x);
        mx = fmaxf(mx, bf2f(w8[1]) * A + B + xa.y);
        mx = fmaxf(mx, bf2f(w8[2]) * A + B + xa.z);
        mx = fmaxf(mx, bf2f(w8[3]) * A + B + xa.w);
        mx = fmaxf(mx, bf2f(w8[4]) * A + B + xb.x);
        mx = fmaxf(mx, bf2f(w8[5]) * A + B + xb.y);
        mx = fmaxf(mx, bf2f(w8[6]) * A + B + xb.z);
        mx = fmaxf(mx, bf2f(w8[7]) * A + B + xb.w);
    }
    #pragma unroll
    for (int off = 1; off < 64; off <<= 1) mx = fmaxf(mx, __shfl_xor(mx, off));
    __shared__ float red[4];
    if ((tid & 63) == 0) red[tid >> 6] = mx;
    __syncthreads();
    if (tid == 0)
        outp[b * 256 + o] = fmaxf(fmaxf(red[0], red[1]), fmaxf(red[2], red[3]));
}

extern "C" void kernel_launch(void* const* d_in, const int* in_sizes, int n_in,
                              void* d_out, int out_size, void* d_ws, size_t ws_size,
                              hipStream_t stream) {
    const float* x     = (const float*)d_in[0];
    const float* Wg    = (const float*)d_in[1];
    const float* bg    = (const float*)d_in[2];
    const float* Wt    = (const float*)d_in[3];
    const float* bt    = (const float*)d_in[4];
    const float* Wp    = (const float*)d_in[5];
    const float* bp    = (const float*)d_in[6];
    const float* Ww    = (const float*)d_in[7];
    const float* bw    = (const float*)d_in[8];
    const float* gamma = (const float*)d_in[9];
    const float* beta  = (const float*)d_in[10];
    float* outp = (float*)d_out;

    char* ws = (char*)d_ws;
    size_t off = 0;
    auto alloc = [&](size_t bytes) -> void* {
        void* p = ws + off;
        off = (off + bytes + 255) & ~(size_t)255;
        return p;
    };
    short* W_all = (short*)alloc((size_t)384 * 256 * 2);
    short* Ww16  = (short*)alloc((size_t)256 * 128 * 2);
    float* b_all = (float*)alloc((size_t)384 * 4);
    short* OutT  = (short*)alloc((size_t)8 * 4096 * 128 * 2);
    short* Kmat  = (short*)alloc((size_t)8 * 1024 * 128 * 2);
    short* Vmat  = (short*)alloc((size_t)8 * 128 * 1024 * 2);
    short* Ybuf  = (short*)alloc((size_t)8 * 4096 * 128 * 2);
    short* wy    = (short*)alloc((size_t)8 * 256 * 4096 * 2);
    float* stats = (float*)alloc((size_t)256 * 2 * 4);

    k0_prep<<<512, 256, 0, stream>>>(Wg, Wt, Wp, bg, bt, bp, Ww, W_all, Ww16, b_all, stats);
    k1_conv<<<dim3(32, 3, 8), 256, 0, stream>>>(x, W_all, b_all, OutT, Kmat, Vmat);
    k3_attn<<<512, 256, 0, stream>>>(OutT, Kmat, Vmat, Ybuf);
    k4_wy<<<dim3(16, 4, 8), 256, 0, stream>>>(Ww16, Ybuf, bw, wy, stats);
    k5_bnmax<<<2048, 256, 0, stream>>>(wy, x, stats, gamma, beta, outp);
}

// Round 9
// 97.549 us; speedup vs baseline: 1.4491x; 1.0269x over previous
//
#include <hip/hip_runtime.h>
#include <hip/hip_bf16.h>
#include <stdint.h>

using f32x4  = __attribute__((ext_vector_type(4))) float;
using bf16x8 = __attribute__((ext_vector_type(8))) short;
using short4v = __attribute__((ext_vector_type(4))) short;

#define DEVINL static __device__ __forceinline__

DEVINL short f2bf(float f) {
    union { float f; uint32_t u; } v; v.f = f;
    uint32_t r = (v.u + 0x7FFFu + ((v.u >> 16) & 1u)) >> 16;   // RNE
    return (short)(uint16_t)r;
}
DEVINL float bf2f(short s) {
    union { uint32_t u; float f; } v; v.u = ((uint32_t)(uint16_t)s) << 16;
    return v.f;
}
DEVINL float fexp2(float x) {            // raw v_exp_f32 (2^x)
    float r;
    asm("v_exp_f32 %0, %1" : "=v"(r) : "v"(x));
    return r;
}

// async global -> LDS, 16B per lane. LDS dest is wave-uniform base + lane*16 (HW).
DEVINL void gld16(const short* g, short* l) {
    __builtin_amdgcn_global_load_lds(
        (const __attribute__((address_space(1))) unsigned int*)g,
        (__attribute__((address_space(3))) unsigned int*)l, 16, 0, 0);
}

#define LOG2E 1.44269504f

// ---------------- K0: weight prep (fp32 -> bf16, stack Wg|Wt|Wp) ----------
__global__ __launch_bounds__(256) void k0_prep(
        const float* __restrict__ Wg, const float* __restrict__ Wt, const float* __restrict__ Wp,
        const float* __restrict__ bg, const float* __restrict__ bt, const float* __restrict__ bp,
        const float* __restrict__ Ww,
        short* __restrict__ W_all, short* __restrict__ Ww16, float* __restrict__ b_all) {
    int i = blockIdx.x * 256 + threadIdx.x;
    if (i < 384 * 256) {
        int r = i >> 8, c = i & 255;
        float v = (r < 128) ? Wg[r * 256 + c]
                : (r < 256) ? Wt[(r - 128) * 256 + c] * LOG2E
                            : Wp[(r - 256) * 256 + c];
        W_all[i] = f2bf(v);
    } else if (i < 384 * 256 + 256 * 128) {
        int j = i - 384 * 256;
        Ww16[j] = f2bf(Ww[j]);
    }
    if (i < 384) {
        b_all[i] = (i < 128) ? bg[i] : (i < 256) ? bt[i - 128] * LOG2E : bp[i - 256];
    }
}

// ---------------- K1: fused conv1x1 x3 GEMM + fused 2x2 maxpool epilogues ----------
// otile 0 (g)    -> pooled, transposed into Vmat[b][c][m]
// otile 1 (theta)-> OutT[b][n][128] (log2e-scaled logits)
// otile 2 (phi)  -> pooled into Kmat[b][m][c]
__global__ __launch_bounds__(256) void k1_conv(const float* __restrict__ x,
        const short* __restrict__ W_all, const float* __restrict__ b_all,
        short* __restrict__ OutT, short* __restrict__ Kmat, short* __restrict__ Vmat) {
    __shared__ short xs[128 * 32];       // [n][c], 16B-chunk XOR swizzle: ch ^= (n>>1)&3
    __shared__ short obuf[128 * 128];    // [n][o], 16B-chunk XOR swizzle: ch ^= n&15
    const int ntile = blockIdx.x;           // 32
    const int otile = blockIdx.y;           // 3
    const int b     = blockIdx.z;           // 8
    const int tid  = threadIdx.x;
    const int lane = tid & 63;
    const int wave = tid >> 6;
    const int wn = wave >> 1, wo = wave & 1;
    const int l15 = lane & 15, lh = lane >> 4;

    f32x4 acc[4][4];
    #pragma unroll
    for (int i = 0; i < 4; i++)
        #pragma unroll
        for (int j = 0; j < 4; j++) acc[i][j] = f32x4{0.f, 0.f, 0.f, 0.f};

    const int n0 = ntile * 128;
    const int ob = otile * 128 + wo * 64;
    const float* xb = x + (size_t)b * 256 * 4096;

    const int srow_base = (lane & 15) + wave * 16;    // + p*64
    const int sc0 = (lane >> 4) * 8;                  // channel chunk base

    for (int kt = 0; kt < 8; kt++) {
        __syncthreads();
        #pragma unroll
        for (int p = 0; p < 2; p++) {
            int row = srow_base + p * 64;
            const float* xp = xb + (size_t)(kt * 32 + sc0) * 4096 + n0 + row;
            bf16x8 w8;
            #pragma unroll
            for (int j = 0; j < 8; j++) w8[j] = f2bf(xp[(size_t)j * 4096]);
            int ch = (sc0 >> 3) ^ ((row >> 1) & 3);
            *(bf16x8*)&xs[row * 32 + ch * 8] = w8;
        }
        __syncthreads();

        bf16x8 a[4], w[4];
        #pragma unroll
        for (int nf = 0; nf < 4; nf++) {
            int row = wn * 64 + nf * 16 + l15;
            int ch  = lh ^ ((row >> 1) & 3);
            a[nf] = *(const bf16x8*)&xs[row * 32 + ch * 8];
        }
        #pragma unroll
        for (int of = 0; of < 4; of++)
            w[of] = *(const bf16x8*)(W_all + (size_t)(ob + of * 16 + l15) * 256 + kt * 32 + lh * 8);
        #pragma unroll
        for (int nf = 0; nf < 4; nf++)
            #pragma unroll
            for (int of = 0; of < 4; of++)
                acc[nf][of] = __builtin_amdgcn_mfma_f32_16x16x32_bf16(a[nf], w[of], acc[nf][of], 0, 0, 0);
    }

    // write accumulators (+bias) into XOR-swizzled obuf
    #pragma unroll
    for (int of = 0; of < 4; of++) {
        int ocol = wo * 64 + of * 16 + l15;
        float bias = b_all[otile * 128 + ocol];
        #pragma unroll
        for (int nf = 0; nf < 4; nf++)
            #pragma unroll
            for (int r = 0; r < 4; r++) {
                int n  = wn * 64 + nf * 16 + lh * 4 + r;
                int ch = (ocol >> 3) ^ (n & 15);
                obuf[n * 128 + ch * 8 + (ocol & 7)] = f2bf(acc[nf][of][r] + bias);
            }
    }
    __syncthreads();

    if (otile == 1) {
        #pragma unroll
        for (int p = 0; p < 8; p++) {
            int n  = wave * 4 + lh + p * 16;
            int ch = l15 ^ (n & 15);
            bf16x8 v = *(const bf16x8*)&obuf[n * 128 + ch * 8];
            *(bf16x8*)(OutT + ((size_t)b * 4096 + n0 + n) * 128 + l15 * 8) = v;
        }
    } else if (otile == 2) {
        // phi: 2x2 maxpool -> Kmat[b][m][c]
        const int wp = tid >> 3;
        const int cc = (tid & 7) * 16;
        short* kdst = Kmat + ((size_t)b * 1024 + ntile * 32 + wp) * 128 + cc;
        #pragma unroll
        for (int cblk = 0; cblk < 2; cblk++) {
            const int chunk = (cc >> 3) + cblk;
            float mx[8];
            #pragma unroll
            for (int j = 0; j < 8; j++) mx[j] = -1e30f;
            #pragma unroll
            for (int q4 = 0; q4 < 4; q4++) {
                int n = (q4 >> 1) * 64 + 2 * wp + (q4 & 1);
                bf16x8 v = *(const bf16x8*)&obuf[n * 128 + ((chunk ^ (n & 15)) * 8)];
                #pragma unroll
                for (int j = 0; j < 8; j++) mx[j] = fmaxf(mx[j], bf2f(v[j]));
            }
            bf16x8 vo;
            #pragma unroll
            for (int j = 0; j < 8; j++) vo[j] = f2bf(mx[j]);
            *(bf16x8*)(kdst + cblk * 8) = vo;
        }
    } else {
        // g: 2x2 maxpool + transpose -> Vmat[b][c][m]
        const int c   = tid >> 1;
        const int wp0 = (tid & 1) * 16;
        const int chb = c >> 3, cl = c & 7;
        #pragma unroll
        for (int half = 0; half < 2; half++) {
            bf16x8 vo;
            #pragma unroll
            for (int j = 0; j < 8; j++) {
                int wp = wp0 + half * 8 + j;
                float mx = -1e30f;
                #pragma unroll
                for (int q4 = 0; q4 < 4; q4++) {
                    int n = (q4 >> 1) * 64 + 2 * wp + (q4 & 1);
                    mx = fmaxf(mx, bf2f(obuf[n * 128 + ((chb ^ (n & 15)) * 8) + cl]));
                }
                vo[j] = f2bf(mx);
            }
            *(bf16x8*)(Vmat + ((size_t)b * 128 + c) * 1024 + ntile * 32 + wp0 + half * 8) = vo;
        }
    }
}

// ---------------- K3: flash attention + fused Ww GEMM epilogue ----------------
// Main loop unchanged (4 waves x 16 rows, dbuf gld16, counted vmcnt, swapped QK^T).
// Epilogue: y -> bf16 -> per-wave LDS bounce -> wy = Ww @ y^T + bias (k4's math).
__global__ __launch_bounds__(256) void k3_attn(const short* __restrict__ OutT,
        const short* __restrict__ Kmat, const short* __restrict__ Vmat,
        const short* __restrict__ Ww16, const float* __restrict__ bw,
        short* __restrict__ wy) {
    __shared__ short sK[2][64 * 128];   // [m][c], chunk-XOR-swizzled content
    __shared__ short sV[2][128 * 64];   // [c][m], chunk-XOR-swizzled content
    __shared__ short sP[4][16 * 64];    // per-wave P / y bounce (A/B-layout, swizzled)

    const int bid = blockIdx.x;         // 512
    const int b   = bid & 7;
    const int nt  = bid >> 3;           // 64 tiles of 64 rows
    const int tid = threadIdx.x;
    const int lane = tid & 63;
    const int wave = tid >> 6;
    const int l15 = lane & 15, lh = lane >> 4;
    const int n0 = nt * 64 + wave * 16;

    const short* Kb = Kmat + (size_t)b * 1024 * 128;
    const short* Vb = Vmat + (size_t)b * 128 * 1024;
    short* sPw = sP[wave];

    auto STAGE = [&](int t, int bufi) {
        const int m0 = t * 64;
        #pragma unroll
        for (int i = 0; i < 4; i++) {
            const int segb = (i * 4 + wave) * 64;          // wave-uniform, chunk units
            const int rowK = (segb >> 4) + (lane >> 4);
            const int chkK = lane & 15;
            gld16(Kb + (size_t)(m0 + rowK) * 128 + ((chkK ^ (rowK & 15)) << 3),
                  &sK[bufi][segb * 8]);
            const int rowV = (segb >> 3) + (lane >> 3);
            const int chkV = lane & 7;
            gld16(Vb + (size_t)rowV * 1024 + m0 + ((chkV ^ (rowV & 7)) << 3),
                  &sV[bufi][segb * 8]);
        }
    };

    bf16x8 q[4];
    {
        const short* qrow = OutT + ((size_t)b * 4096 + n0 + l15) * 128;
        #pragma unroll
        for (int ks = 0; ks < 4; ks++)
            q[ks] = *(const bf16x8*)(qrow + ks * 32 + lh * 8);
    }

    f32x4 y[8];
    #pragma unroll
    for (int cf = 0; cf < 8; cf++) y[cf] = f32x4{0.f, 0.f, 0.f, 0.f};
    float mrun = -1e30f, lrun = 0.f;    // per-lane: q-row = l15 (replicated over lh); base-2

    STAGE(0, 0);
    int cur = 0;

    for (int t = 0; t < 16; t++) {
        if (t < 15) {
            STAGE(t + 1, cur ^ 1);
            asm volatile("s_waitcnt vmcnt(8)" ::: "memory");
        } else {
            asm volatile("s_waitcnt vmcnt(0)" ::: "memory");
        }
        __builtin_amdgcn_s_barrier();
        __builtin_amdgcn_sched_barrier(0);

        const short* cK = sK[cur];
        const short* cV = sV[cur];

        f32x4 S[4];
        #pragma unroll
        for (int mf = 0; mf < 4; mf++) S[mf] = f32x4{0.f, 0.f, 0.f, 0.f};
        #pragma unroll
        for (int ks = 0; ks < 4; ks++) {
            bf16x8 kf[4];
            #pragma unroll
            for (int mf = 0; mf < 4; mf++) {
                int mrow = mf * 16 + l15;
                int jj   = ks * 4 + lh;
                kf[mf] = *(const bf16x8*)&cK[mrow * 128 + ((jj ^ (mrow & 15)) << 3)];
            }
            __builtin_amdgcn_s_setprio(1);
            #pragma unroll
            for (int mf = 0; mf < 4; mf++)
                S[mf] = __builtin_amdgcn_mfma_f32_16x16x32_bf16(kf[mf], q[ks], S[mf], 0, 0, 0);
            __builtin_amdgcn_s_setprio(0);
        }

        // lane-local softmax (base 2)
        float pm = S[0][0];
        #pragma unroll
        for (int mf = 0; mf < 4; mf++)
            #pragma unroll
            for (int r = 0; r < 4; r++) pm = fmaxf(pm, S[mf][r]);
        pm = fmaxf(pm, __shfl_xor(pm, 16));
        pm = fmaxf(pm, __shfl_xor(pm, 32));

        if (__any(pm > mrun + 8.656f)) {       // defer-max (6 nats in log2 units)
            float mnew  = fmaxf(mrun, pm);
            float alpha = fexp2(mrun - mnew);
            mrun = mnew;
            lrun *= alpha;
            float aR[4];
            #pragma unroll
            for (int r = 0; r < 4; r++) aR[r] = __shfl(alpha, lh * 4 + r);
            #pragma unroll
            for (int cf = 0; cf < 8; cf++)
                #pragma unroll
                for (int r = 0; r < 4; r++) y[cf][r] *= aR[r];
        }
        float rs = 0.f;
        #pragma unroll
        for (int mf = 0; mf < 4; mf++)
            #pragma unroll
            for (int r = 0; r < 4; r++) {
                float p = fexp2(S[mf][r] - mrun);
                S[mf][r] = p;
                rs += p;
            }
        rs += __shfl_xor(rs, 16);
        rs += __shfl_xor(rs, 32);
        lrun += rs;

        // P -> per-wave LDS, vectorized 8B writes, 8B-subchunk XOR swizzle
        #pragma unroll
        for (int mf = 0; mf < 4; mf++) {
            short4v pk = { f2bf(S[mf][0]), f2bf(S[mf][1]), f2bf(S[mf][2]), f2bf(S[mf][3]) };
            *(short4v*)&sPw[(l15 << 6) + (((mf * 4 + lh) ^ l15) << 2)] = pk;
        }

        // y += P @ V^T
        #pragma unroll
        for (int ks2 = 0; ks2 < 2; ks2++) {
            int u0 = ks2 * 8 + lh * 2;
            short4v lo = *(const short4v*)&sPw[(l15 << 6) + (((u0)     ^ l15) << 2)];
            short4v hi = *(const short4v*)&sPw[(l15 << 6) + (((u0 + 1) ^ l15) << 2)];
            bf16x8 pa = { lo.x, lo.y, lo.z, lo.w, hi.x, hi.y, hi.z, hi.w };
            int jj = ks2 * 4 + lh;
            __builtin_amdgcn_s_setprio(1);
            #pragma unroll
            for (int cf = 0; cf < 8; cf++) {
                int crow = cf * 16 + l15;
                bf16x8 vf = *(const bf16x8*)&cV[crow * 64 + ((jj ^ (crow & 7)) << 3)];
                y[cf] = __builtin_amdgcn_mfma_f32_16x16x32_bf16(pa, vf, y[cf], 0, 0, 0);
            }
            __builtin_amdgcn_s_setprio(0);
        }

        __builtin_amdgcn_sched_barrier(0);
        __builtin_amdgcn_s_barrier();       // protect buf[cur] from next-iter overwrite
        cur ^= 1;
    }

    // ---- epilogue: normalize, bounce y -> B-fragments, wy = Ww @ y^T + bias ----
    float linv[4];
    #pragma unroll
    for (int r = 0; r < 4; r++) linv[r] = 1.f / __shfl(lrun, lh * 4 + r);

    bf16x8 by[4];
    #pragma unroll
    for (int h = 0; h < 2; h++) {
        // write this 64-c half into sPw as [n(16)][c(64)] with 8B-subchunk XOR swizzle
        #pragma unroll
        for (int cfl = 0; cfl < 4; cfl++) {
            int cf = h * 4 + cfl;
            #pragma unroll
            for (int r = 0; r < 4; r++) {
                int n = lh * 4 + r;
                int chunk4 = cfl * 4 + (l15 >> 2);
                sPw[n * 64 + ((chunk4 ^ n) << 2) + (l15 & 3)] = f2bf(y[cf][r] * linv[r]);
            }
        }
        // read two B fragments (lane l15 = n-row, k-chunks of this half)
        #pragma unroll
        for (int ks2 = 0; ks2 < 2; ks2++) {
            int u0 = ks2 * 8 + lh * 2;
            short4v lo = *(const short4v*)&sPw[(l15 << 6) + (((u0)     ^ l15) << 2)];
            short4v hi = *(const short4v*)&sPw[(l15 << 6) + (((u0 + 1) ^ l15) << 2)];
            by[h * 2 + ks2] = bf16x8{ lo.x, lo.y, lo.z, lo.w, hi.x, hi.y, hi.z, hi.w };
        }
    }

    // k4's GEMM body: A = Ww rows (o), B = y rows (n); D col=l15=n, row=lh*4+r=o
    #pragma unroll
    for (int of = 0; of < 16; of++) {
        bf16x8 aw[4];
        #pragma unroll
        for (int ks = 0; ks < 4; ks++)
            aw[ks] = *(const bf16x8*)(Ww16 + (size_t)(of * 16 + l15) * 128 + ks * 32 + lh * 8);
        f32x4 acc = f32x4{0.f, 0.f, 0.f, 0.f};
        #pragma unroll
        for (int ks = 0; ks < 4; ks++)
            acc = __builtin_amdgcn_mfma_f32_16x16x32_bf16(aw[ks], by[ks], acc, 0, 0, 0);
        #pragma unroll
        for (int r = 0; r < 4; r++) {
            int o = of * 16 + lh * 4 + r;
            wy[((size_t)b * 256 + o) * 4096 + n0 + l15] = f2bf(acc[r] + bw[o]);
        }
    }
}

// ---------------- K4s: BN stats from wy (direct store, no atomics) ----------------
__global__ __launch_bounds__(256) void k4s_stats(const short* __restrict__ wy,
        float* __restrict__ stats) {
    const int o = blockIdx.x;      // 256
    const int tid = threadIdx.x;
    float s = 0.f, s2 = 0.f;
    #pragma unroll
    for (int b = 0; b < 8; b++) {
        const short* p = wy + ((size_t)b * 256 + o) * 4096;
        #pragma unroll
        for (int i = 0; i < 2; i++) {
            bf16x8 v = *(const bf16x8*)(p + (tid + i * 256) * 8);
            #pragma unroll
            for (int j = 0; j < 8; j++) {
                float f = bf2f(v[j]);
                s += f; s2 += f * f;
            }
        }
    }
    #pragma unroll
    for (int off = 1; off < 64; off <<= 1) { s += __shfl_xor(s, off); s2 += __shfl_xor(s2, off); }
    __shared__ float red[4][2];
    if ((tid & 63) == 0) { red[tid >> 6][0] = s; red[tid >> 6][1] = s2; }
    __syncthreads();
    if (tid == 0) {
        stats[o * 2]     = red[0][0] + red[1][0] + red[2][0] + red[3][0];
        stats[o * 2 + 1] = red[0][1] + red[1][1] + red[2][1] + red[3][1];
    }
}

// ---------------- K5: BN finalize + apply + residual + global spatial max ----------------
__global__ __launch_bounds__(256) void k5_bnmax(const short* __restrict__ wy,
        const float* __restrict__ x, const float* __restrict__ stats,
        const float* __restrict__ gamma, const float* __restrict__ beta,
        float* __restrict__ outp) {
    int b = blockIdx.x >> 8;
    int o = blockIdx.x & 255;
    int tid = threadIdx.x;
    float mean = stats[o * 2] * (1.f / 32768.f);
    float var  = stats[o * 2 + 1] * (1.f / 32768.f) - mean * mean;
    float rstd = rsqrtf(var + 1e-5f);
    float A = rstd * gamma[o];
    float B = beta[o] - mean * A;
    const short* pw = wy + ((size_t)b * 256 + o) * 4096;
    const float* px = x + ((size_t)b * 256 + o) * 4096;
    float mx = -1e30f;
    #pragma unroll
    for (int j = 0; j < 2; j++) {
        int e = (tid + j * 256) * 8;
        bf16x8 w8 = *(const bf16x8*)(pw + e);
        float4 xa = *(const float4*)(px + e);
        float4 xb = *(const float4*)(px + e + 4);
        mx = fmaxf(mx, bf2f(w8[0]) * A + B + xa.x);
        mx = fmaxf(mx, bf2f(w8[1]) * A + B + xa.y);
        mx = fmaxf(mx, bf2f(w8[2]) * A + B + xa.z);
        mx = fmaxf(mx, bf2f(w8[3]) * A + B + xa.w);
        mx = fmaxf(mx, bf2f(w8[4]) * A + B + xb.x);
        mx = fmaxf(mx, bf2f(w8[5]) * A + B + xb.y);
        mx = fmaxf(mx, bf2f(w8[6]) * A + B + xb.z);
        mx = fmaxf(mx, bf2f(w8[7]) * A + B + xb.w);
    }
    #pragma unroll
    for (int off = 1; off < 64; off <<= 1) mx = fmaxf(mx, __shfl_xor(mx, off));
    __shared__ float red[4];
    if ((tid & 63) == 0) red[tid >> 6] = mx;
    __syncthreads();
    if (tid == 0)
        outp[b * 256 + o] = fmaxf(fmaxf(red[0], red[1]), fmaxf(red[2], red[3]));
}

extern "C" void kernel_launch(void* const* d_in, const int* in_sizes, int n_in,
                              void* d_out, int out_size, void* d_ws, size_t ws_size,
                              hipStream_t stream) {
    const float* x     = (const float*)d_in[0];
    const float* Wg    = (const float*)d_in[1];
    const float* bg    = (const float*)d_in[2];
    const float* Wt    = (const float*)d_in[3];
    const float* bt    = (const float*)d_in[4];
    const float* Wp    = (const float*)d_in[5];
    const float* bp    = (const float*)d_in[6];
    const float* Ww    = (const float*)d_in[7];
    const float* bw    = (const float*)d_in[8];
    const float* gamma = (const float*)d_in[9];
    const float* beta  = (const float*)d_in[10];
    float* outp = (float*)d_out;

    char* ws = (char*)d_ws;
    size_t off = 0;
    auto alloc = [&](size_t bytes) -> void* {
        void* p = ws + off;
        off = (off + bytes + 255) & ~(size_t)255;
        return p;
    };
    short* W_all = (short*)alloc((size_t)384 * 256 * 2);
    short* Ww16  = (short*)alloc((size_t)256 * 128 * 2);
    float* b_all = (float*)alloc((size_t)384 * 4);
    short* OutT  = (short*)alloc((size_t)8 * 4096 * 128 * 2);
    short* Kmat  = (short*)alloc((size_t)8 * 1024 * 128 * 2);
    short* Vmat  = (short*)alloc((size_t)8 * 128 * 1024 * 2);
    short* wy    = (short*)alloc((size_t)8 * 256 * 4096 * 2);
    float* stats = (float*)alloc((size_t)256 * 2 * 4);

    k0_prep<<<512, 256, 0, stream>>>(Wg, Wt, Wp, bg, bt, bp, Ww, W_all, Ww16, b_all);
    k1_conv<<<dim3(32, 3, 8), 256, 0, stream>>>(x, W_all, b_all, OutT, Kmat, Vmat);
    k3_attn<<<512, 256, 0, stream>>>(OutT, Kmat, Vmat, Ww16, bw, wy);
    k4s_stats<<<256, 256, 0, stream>>>(wy, stats);
    k5_bnmax<<<2048, 256, 0, stream>>>(wy, x, stats, gamma, beta, outp);
}

// Round 10
// 88.933 us; speedup vs baseline: 1.5895x; 1.0969x over previous
//
#include <hip/hip_runtime.h>
#include <hip/hip_bf16.h>
#include <stdint.h>

using f32x4  = __attribute__((ext_vector_type(4))) float;
using bf16x8 = __attribute__((ext_vector_type(8))) short;
using short4v = __attribute__((ext_vector_type(4))) short;

#define DEVINL static __device__ __forceinline__

DEVINL short f2bf(float f) {
    union { float f; uint32_t u; } v; v.f = f;
    uint32_t r = (v.u + 0x7FFFu + ((v.u >> 16) & 1u)) >> 16;   // RNE
    return (short)(uint16_t)r;
}
DEVINL float bf2f(short s) {
    union { uint32_t u; float f; } v; v.u = ((uint32_t)(uint16_t)s) << 16;
    return v.f;
}
DEVINL float fexp2(float x) {            // raw v_exp_f32 (2^x)
    float r;
    asm("v_exp_f32 %0, %1" : "=v"(r) : "v"(x));
    return r;
}

// async global -> LDS, 16B per lane. LDS dest is wave-uniform base + lane*16 (HW).
DEVINL void gld16(const short* g, short* l) {
    __builtin_amdgcn_global_load_lds(
        (const __attribute__((address_space(1))) unsigned int*)g,
        (__attribute__((address_space(3))) unsigned int*)l, 16, 0, 0);
}

#define LOG2E 1.44269504f

// ---------------- K0: weight prep (fp32 -> bf16, stack Wg|Wt|Wp) ----------
__global__ __launch_bounds__(256) void k0_prep(
        const float* __restrict__ Wg, const float* __restrict__ Wt, const float* __restrict__ Wp,
        const float* __restrict__ bg, const float* __restrict__ bt, const float* __restrict__ bp,
        const float* __restrict__ Ww,
        short* __restrict__ W_all, short* __restrict__ Ww16, float* __restrict__ b_all) {
    int i = blockIdx.x * 256 + threadIdx.x;
    if (i < 384 * 256) {
        int r = i >> 8, c = i & 255;
        float v = (r < 128) ? Wg[r * 256 + c]
                : (r < 256) ? Wt[(r - 128) * 256 + c] * LOG2E
                            : Wp[(r - 256) * 256 + c];
        W_all[i] = f2bf(v);
    } else if (i < 384 * 256 + 256 * 128) {
        int j = i - 384 * 256;
        Ww16[j] = f2bf(Ww[j]);
    }
    if (i < 384) {
        b_all[i] = (i < 128) ? bg[i] : (i < 256) ? bt[i - 128] * LOG2E : bp[i - 256];
    }
}

// ---------------- K1: fused conv1x1 x3 GEMM + fused 2x2 maxpool epilogues ----------
__global__ __launch_bounds__(256) void k1_conv(const float* __restrict__ x,
        const short* __restrict__ W_all, const float* __restrict__ b_all,
        short* __restrict__ OutT, short* __restrict__ Kmat, short* __restrict__ Vmat) {
    __shared__ short xs[128 * 32];       // [n][c], 16B-chunk XOR swizzle: ch ^= (n>>1)&3
    __shared__ short obuf[128 * 128];    // [n][o], 16B-chunk XOR swizzle: ch ^= n&15
    const int ntile = blockIdx.x;           // 32
    const int otile = blockIdx.y;           // 3
    const int b     = blockIdx.z;           // 8
    const int tid  = threadIdx.x;
    const int lane = tid & 63;
    const int wave = tid >> 6;
    const int wn = wave >> 1, wo = wave & 1;
    const int l15 = lane & 15, lh = lane >> 4;

    f32x4 acc[4][4];
    #pragma unroll
    for (int i = 0; i < 4; i++)
        #pragma unroll
        for (int j = 0; j < 4; j++) acc[i][j] = f32x4{0.f, 0.f, 0.f, 0.f};

    const int n0 = ntile * 128;
    const int ob = otile * 128 + wo * 64;
    const float* xb = x + (size_t)b * 256 * 4096;

    const int srow_base = (lane & 15) + wave * 16;    // + p*64
    const int sc0 = (lane >> 4) * 8;                  // channel chunk base

    for (int kt = 0; kt < 8; kt++) {
        __syncthreads();
        #pragma unroll
        for (int p = 0; p < 2; p++) {
            int row = srow_base + p * 64;
            const float* xp = xb + (size_t)(kt * 32 + sc0) * 4096 + n0 + row;
            bf16x8 w8;
            #pragma unroll
            for (int j = 0; j < 8; j++) w8[j] = f2bf(xp[(size_t)j * 4096]);
            int ch = (sc0 >> 3) ^ ((row >> 1) & 3);
            *(bf16x8*)&xs[row * 32 + ch * 8] = w8;
        }
        __syncthreads();

        bf16x8 a[4], w[4];
        #pragma unroll
        for (int nf = 0; nf < 4; nf++) {
            int row = wn * 64 + nf * 16 + l15;
            int ch  = lh ^ ((row >> 1) & 3);
            a[nf] = *(const bf16x8*)&xs[row * 32 + ch * 8];
        }
        #pragma unroll
        for (int of = 0; of < 4; of++)
            w[of] = *(const bf16x8*)(W_all + (size_t)(ob + of * 16 + l15) * 256 + kt * 32 + lh * 8);
        #pragma unroll
        for (int nf = 0; nf < 4; nf++)
            #pragma unroll
            for (int of = 0; of < 4; of++)
                acc[nf][of] = __builtin_amdgcn_mfma_f32_16x16x32_bf16(a[nf], w[of], acc[nf][of], 0, 0, 0);
    }

    #pragma unroll
    for (int of = 0; of < 4; of++) {
        int ocol = wo * 64 + of * 16 + l15;
        float bias = b_all[otile * 128 + ocol];
        #pragma unroll
        for (int nf = 0; nf < 4; nf++)
            #pragma unroll
            for (int r = 0; r < 4; r++) {
                int n  = wn * 64 + nf * 16 + lh * 4 + r;
                int ch = (ocol >> 3) ^ (n & 15);
                obuf[n * 128 + ch * 8 + (ocol & 7)] = f2bf(acc[nf][of][r] + bias);
            }
    }
    __syncthreads();

    if (otile == 1) {
        #pragma unroll
        for (int p = 0; p < 8; p++) {
            int n  = wave * 4 + lh + p * 16;
            int ch = l15 ^ (n & 15);
            bf16x8 v = *(const bf16x8*)&obuf[n * 128 + ch * 8];
            *(bf16x8*)(OutT + ((size_t)b * 4096 + n0 + n) * 128 + l15 * 8) = v;
        }
    } else if (otile == 2) {
        // phi: 2x2 maxpool -> Kmat[b][m][c]
        const int wp = tid >> 3;
        const int cc = (tid & 7) * 16;
        short* kdst = Kmat + ((size_t)b * 1024 + ntile * 32 + wp) * 128 + cc;
        #pragma unroll
        for (int cblk = 0; cblk < 2; cblk++) {
            const int chunk = (cc >> 3) + cblk;
            float mx[8];
            #pragma unroll
            for (int j = 0; j < 8; j++) mx[j] = -1e30f;
            #pragma unroll
            for (int q4 = 0; q4 < 4; q4++) {
                int n = (q4 >> 1) * 64 + 2 * wp + (q4 & 1);
                bf16x8 v = *(const bf16x8*)&obuf[n * 128 + ((chunk ^ (n & 15)) * 8)];
                #pragma unroll
                for (int j = 0; j < 8; j++) mx[j] = fmaxf(mx[j], bf2f(v[j]));
            }
            bf16x8 vo;
            #pragma unroll
            for (int j = 0; j < 8; j++) vo[j] = f2bf(mx[j]);
            *(bf16x8*)(kdst + cblk * 8) = vo;
        }
    } else {
        // g: 2x2 maxpool + transpose -> Vmat[b][c][m]
        const int c   = tid >> 1;
        const int wp0 = (tid & 1) * 16;
        const int chb = c >> 3, cl = c & 7;
        #pragma unroll
        for (int half = 0; half < 2; half++) {
            bf16x8 vo;
            #pragma unroll
            for (int j = 0; j < 8; j++) {
                int wp = wp0 + half * 8 + j;
                float mx = -1e30f;
                #pragma unroll
                for (int q4 = 0; q4 < 4; q4++) {
                    int n = (q4 >> 1) * 64 + 2 * wp + (q4 & 1);
                    mx = fmaxf(mx, bf2f(obuf[n * 128 + ((chb ^ (n & 15)) * 8) + cl]));
                }
                vo[j] = f2bf(mx);
            }
            *(bf16x8*)(Vmat + ((size_t)b * 128 + c) * 1024 + ntile * 32 + wp0 + half * 8) = vo;
        }
    }
}

// ---------------- K3: flash attention + block-cooperative Ww GEMM epilogue ----------
__global__ __launch_bounds__(256) void k3_attn(const short* __restrict__ OutT,
        const short* __restrict__ Kmat, const short* __restrict__ Vmat,
        const short* __restrict__ Ww16, const float* __restrict__ bw,
        short* __restrict__ wy) {
    // unioned LDS: main loop {sK dbuf 16K shorts | sV dbuf 16K shorts... } / epilogue {Ytile, sOut}
    __shared__ short smem[36864];       // 72 KB
    short* const sKb = smem;            // [2][64*128]
    short* const sVb = smem + 16384;    // [2][128*64]
    short* const sPb = smem + 32768;    // [4][16*64]

    const int bid = blockIdx.x;         // 512
    const int b   = bid & 7;
    const int nt  = bid >> 3;           // 64 tiles of 64 rows
    const int tid = threadIdx.x;
    const int lane = tid & 63;
    const int wave = tid >> 6;
    const int l15 = lane & 15, lh = lane >> 4;
    const int nblk = nt * 64;
    const int n0 = nblk + wave * 16;

    const short* Kb = Kmat + (size_t)b * 1024 * 128;
    const short* Vb = Vmat + (size_t)b * 128 * 1024;
    short* sPw = sPb + wave * 1024;

    auto STAGE = [&](int t, int bufi) {
        const int m0 = t * 64;
        #pragma unroll
        for (int i = 0; i < 4; i++) {
            const int segb = (i * 4 + wave) * 64;          // wave-uniform, chunk units
            const int rowK = (segb >> 4) + (lane >> 4);
            const int chkK = lane & 15;
            gld16(Kb + (size_t)(m0 + rowK) * 128 + ((chkK ^ (rowK & 15)) << 3),
                  sKb + bufi * 8192 + segb * 8);
            const int rowV = (segb >> 3) + (lane >> 3);
            const int chkV = lane & 7;
            gld16(Vb + (size_t)rowV * 1024 + m0 + ((chkV ^ (rowV & 7)) << 3),
                  sVb + bufi * 8192 + segb * 8);
        }
    };

    bf16x8 q[4];
    {
        const short* qrow = OutT + ((size_t)b * 4096 + n0 + l15) * 128;
        #pragma unroll
        for (int ks = 0; ks < 4; ks++)
            q[ks] = *(const bf16x8*)(qrow + ks * 32 + lh * 8);
    }

    f32x4 y[8];
    #pragma unroll
    for (int cf = 0; cf < 8; cf++) y[cf] = f32x4{0.f, 0.f, 0.f, 0.f};
    float mrun = -1e30f, lrun = 0.f;    // per-lane: q-row = l15 (replicated over lh); base-2

    STAGE(0, 0);
    int cur = 0;

    for (int t = 0; t < 16; t++) {
        if (t < 15) {
            STAGE(t + 1, cur ^ 1);
            asm volatile("s_waitcnt vmcnt(8)" ::: "memory");
        } else {
            asm volatile("s_waitcnt vmcnt(0)" ::: "memory");
        }
        __builtin_amdgcn_s_barrier();
        __builtin_amdgcn_sched_barrier(0);

        const short* cK = sKb + cur * 8192;
        const short* cV = sVb + cur * 8192;

        f32x4 S[4];
        #pragma unroll
        for (int mf = 0; mf < 4; mf++) S[mf] = f32x4{0.f, 0.f, 0.f, 0.f};
        #pragma unroll
        for (int ks = 0; ks < 4; ks++) {
            bf16x8 kf[4];
            #pragma unroll
            for (int mf = 0; mf < 4; mf++) {
                int mrow = mf * 16 + l15;
                int jj   = ks * 4 + lh;
                kf[mf] = *(const bf16x8*)&cK[mrow * 128 + ((jj ^ (mrow & 15)) << 3)];
            }
            __builtin_amdgcn_s_setprio(1);
            #pragma unroll
            for (int mf = 0; mf < 4; mf++)
                S[mf] = __builtin_amdgcn_mfma_f32_16x16x32_bf16(kf[mf], q[ks], S[mf], 0, 0, 0);
            __builtin_amdgcn_s_setprio(0);
        }

        // lane-local softmax (base 2)
        float pm = S[0][0];
        #pragma unroll
        for (int mf = 0; mf < 4; mf++)
            #pragma unroll
            for (int r = 0; r < 4; r++) pm = fmaxf(pm, S[mf][r]);
        pm = fmaxf(pm, __shfl_xor(pm, 16));
        pm = fmaxf(pm, __shfl_xor(pm, 32));

        if (__any(pm > mrun + 8.656f)) {       // defer-max (6 nats in log2 units)
            float mnew  = fmaxf(mrun, pm);
            float alpha = fexp2(mrun - mnew);
            mrun = mnew;
            lrun *= alpha;
            float aR[4];
            #pragma unroll
            for (int r = 0; r < 4; r++) aR[r] = __shfl(alpha, lh * 4 + r);
            #pragma unroll
            for (int cf = 0; cf < 8; cf++)
                #pragma unroll
                for (int r = 0; r < 4; r++) y[cf][r] *= aR[r];
        }
        float rs = 0.f;
        #pragma unroll
        for (int mf = 0; mf < 4; mf++)
            #pragma unroll
            for (int r = 0; r < 4; r++) {
                float p = fexp2(S[mf][r] - mrun);
                S[mf][r] = p;
                rs += p;
            }
        rs += __shfl_xor(rs, 16);
        rs += __shfl_xor(rs, 32);
        lrun += rs;

        // P -> per-wave LDS, vectorized 8B writes, 8B-subchunk XOR swizzle
        #pragma unroll
        for (int mf = 0; mf < 4; mf++) {
            short4v pk = { f2bf(S[mf][0]), f2bf(S[mf][1]), f2bf(S[mf][2]), f2bf(S[mf][3]) };
            *(short4v*)&sPw[(l15 << 6) + (((mf * 4 + lh) ^ l15) << 2)] = pk;
        }

        // y += P @ V^T
        #pragma unroll
        for (int ks2 = 0; ks2 < 2; ks2++) {
            int u0 = ks2 * 8 + lh * 2;
            short4v lo = *(const short4v*)&sPw[(l15 << 6) + (((u0)     ^ l15) << 2)];
            short4v hi = *(const short4v*)&sPw[(l15 << 6) + (((u0 + 1) ^ l15) << 2)];
            bf16x8 pa = { lo.x, lo.y, lo.z, lo.w, hi.x, hi.y, hi.z, hi.w };
            int jj = ks2 * 4 + lh;
            __builtin_amdgcn_s_setprio(1);
            #pragma unroll
            for (int cf = 0; cf < 8; cf++) {
                int crow = cf * 16 + l15;
                bf16x8 vf = *(const bf16x8*)&cV[crow * 64 + ((jj ^ (crow & 7)) << 3)];
                y[cf] = __builtin_amdgcn_mfma_f32_16x16x32_bf16(pa, vf, y[cf], 0, 0, 0);
            }
            __builtin_amdgcn_s_setprio(0);
        }

        __builtin_amdgcn_sched_barrier(0);
        __builtin_amdgcn_s_barrier();       // protect buf[cur] from next-iter overwrite
        cur ^= 1;
    }

    // ---- block-cooperative epilogue: wy[256 o][64 n] = Ww @ Y^T + bias ----
    float linv[4];
    #pragma unroll
    for (int r = 0; r < 4; r++) linv[r] = 1.f / __shfl(lrun, lh * 4 + r);

    // 1) all waves write normalized y into shared Y-tile [64 n][128 c], XOR-swizzled
    short* const Yt = smem;                       // 8192 shorts (reuses sK space)
    #pragma unroll
    for (int cf = 0; cf < 8; cf++) {
        int c = cf * 16 + l15;
        #pragma unroll
        for (int r = 0; r < 4; r++) {
            int n = wave * 16 + lh * 4 + r;
            Yt[n * 128 + (((c >> 3) ^ (n & 15)) << 3) + (c & 7)] = f2bf(y[cf][r] * linv[r]);
        }
    }
    __syncthreads();

    // 2) B-fragments from Y-tile (rows n, conflict-free sK-style reads)
    bf16x8 by[4][4];
    #pragma unroll
    for (int nf = 0; nf < 4; nf++)
        #pragma unroll
        for (int ks = 0; ks < 4; ks++) {
            int n  = nf * 16 + l15;
            int kc = ks * 4 + lh;
            by[nf][ks] = *(const bf16x8*)&Yt[n * 128 + ((kc ^ (n & 15)) << 3)];
        }

    // 3) wave w computes o in [w*64, w*64+64): 16 Ww loads, 64 MFMA
    short* const sOut = smem + 8192 + wave * 4608;   // [64 o][72 stride] per wave
    const int obase = wave * 64;
    #pragma unroll
    for (int of = 0; of < 4; of++) {
        bf16x8 aw[4];
        #pragma unroll
        for (int ks = 0; ks < 4; ks++)
            aw[ks] = *(const bf16x8*)(Ww16 + (size_t)(obase + of * 16 + l15) * 128 + ks * 32 + lh * 8);
        #pragma unroll
        for (int nf = 0; nf < 4; nf++) {
            f32x4 acc = f32x4{0.f, 0.f, 0.f, 0.f};
            #pragma unroll
            for (int ks = 0; ks < 4; ks++)
                acc = __builtin_amdgcn_mfma_f32_16x16x32_bf16(aw[ks], by[nf][ks], acc, 0, 0, 0);
            #pragma unroll
            for (int r = 0; r < 4; r++) {
                int o_loc = of * 16 + lh * 4 + r;
                sOut[o_loc * 72 + nf * 16 + l15] = f2bf(acc[r] + bw[obase + o_loc]);
            }
        }
    }

    // 4) coalesced wy stores: 8 b128 per thread (wave-private region, lgkmcnt-ordered)
    #pragma unroll
    for (int p = 0; p < 8; p++) {
        int o_loc = p * 8 + (lane >> 3);
        int n8    = (lane & 7) * 8;
        bf16x8 v = *(const bf16x8*)&sOut[o_loc * 72 + n8];
        *(bf16x8*)(wy + ((size_t)b * 256 + obase + o_loc) * 4096 + nblk + n8) = v;
    }
}

// ---------------- K4s: BN stats from wy (direct store, no atomics) ----------------
__global__ __launch_bounds__(256) void k4s_stats(const short* __restrict__ wy,
        float* __restrict__ stats) {
    const int o = blockIdx.x;      // 256
    const int tid = threadIdx.x;
    float s = 0.f, s2 = 0.f;
    #pragma unroll
    for (int b = 0; b < 8; b++) {
        const short* p = wy + ((size_t)b * 256 + o) * 4096;
        #pragma unroll
        for (int i = 0; i < 2; i++) {
            bf16x8 v = *(const bf16x8*)(p + (tid + i * 256) * 8);
            #pragma unroll
            for (int j = 0; j < 8; j++) {
                float f = bf2f(v[j]);
                s += f; s2 += f * f;
            }
        }
    }
    #pragma unroll
    for (int off = 1; off < 64; off <<= 1) { s += __shfl_xor(s, off); s2 += __shfl_xor(s2, off); }
    __shared__ float red[4][2];
    if ((tid & 63) == 0) { red[tid >> 6][0] = s; red[tid >> 6][1] = s2; }
    __syncthreads();
    if (tid == 0) {
        stats[o * 2]     = red[0][0] + red[1][0] + red[2][0] + red[3][0];
        stats[o * 2 + 1] = red[0][1] + red[1][1] + red[2][1] + red[3][1];
    }
}

// ---------------- K5: BN finalize + apply + residual + global spatial max ----------------
__global__ __launch_bounds__(256) void k5_bnmax(const short* __restrict__ wy,
        const float* __restrict__ x, const float* __restrict__ stats,
        const float* __restrict__ gamma, const float* __restrict__ beta,
        float* __restrict__ outp) {
    int b = blockIdx.x >> 8;
    int o = blockIdx.x & 255;
    int tid = threadIdx.x;
    float mean = stats[o * 2] * (1.f / 32768.f);
    float var  = stats[o * 2 + 1] * (1.f / 32768.f) - mean * mean;
    float rstd = rsqrtf(var + 1e-5f);
    float A = rstd * gamma[o];
    float B = beta[o] - mean * A;
    const short* pw = wy + ((size_t)b * 256 + o) * 4096;
    const float* px = x + ((size_t)b * 256 + o) * 4096;
    float mx = -1e30f;
    #pragma unroll
    for (int j = 0; j < 2; j++) {
        int e = (tid + j * 256) * 8;
        bf16x8 w8 = *(const bf16x8*)(pw + e);
        float4 xa = *(const float4*)(px + e);
        float4 xb = *(const float4*)(px + e + 4);
        mx = fmaxf(mx, bf2f(w8[0]) * A + B + xa.x);
        mx = fmaxf(mx, bf2f(w8[1]) * A + B + xa.y);
        mx = fmaxf(mx, bf2f(w8[2]) * A + B + xa.z);
        mx = fmaxf(mx, bf2f(w8[3]) * A + B + xa.w);
        mx = fmaxf(mx, bf2f(w8[4]) * A + B + xb.x);
        mx = fmaxf(mx, bf2f(w8[5]) * A + B + xb.y);
        mx = fmaxf(mx, bf2f(w8[6]) * A + B + xb.z);
        mx = fmaxf(mx, bf2f(w8[7]) * A + B + xb.w);
    }
    #pragma unroll
    for (int off = 1; off < 64; off <<= 1) mx = fmaxf(mx, __shfl_xor(mx, off));
    __shared__ float red[4];
    if ((tid & 63) == 0) red[tid >> 6] = mx;
    __syncthreads();
    if (tid == 0)
        outp[b * 256 + o] = fmaxf(fmaxf(red[0], red[1]), fmaxf(red[2], red[3]));
}

extern "C" void kernel_launch(void* const* d_in, const int* in_sizes, int n_in,
                              void* d_out, int out_size, void* d_ws, size_t ws_size,
                              hipStream_t stream) {
    const float* x     = (const float*)d_in[0];
    const float* Wg    = (const float*)d_in[1];
    const float* bg    = (const float*)d_in[2];
    const float* Wt    = (const float*)d_in[3];
    const float* bt    = (const float*)d_in[4];
    const float* Wp    = (const float*)d_in[5];
    const float* bp    = (const float*)d_in[6];
    const float* Ww    = (const float*)d_in[7];
    const float* bw    = (const float*)d_in[8];
    const float* gamma = (const float*)d_in[9];
    const float* beta  = (const float*)d_in[10];
    float* outp = (float*)d_out;

    char* ws = (char*)d_ws;
    size_t off = 0;
    auto alloc = [&](size_t bytes) -> void* {
        void* p = ws + off;
        off = (off + bytes + 255) & ~(size_t)255;
        return p;
    };
    short* W_all = (short*)alloc((size_t)384 * 256 * 2);
    short* Ww16  = (short*)alloc((size_t)256 * 128 * 2);
    float* b_all = (float*)alloc((size_t)384 * 4);
    short* OutT  = (short*)alloc((size_t)8 * 4096 * 128 * 2);
    short* Kmat  = (short*)alloc((size_t)8 * 1024 * 128 * 2);
    short* Vmat  = (short*)alloc((size_t)8 * 128 * 1024 * 2);
    short* wy    = (short*)alloc((size_t)8 * 256 * 4096 * 2);
    float* stats = (float*)alloc((size_t)256 * 2 * 4);

    k0_prep<<<512, 256, 0, stream>>>(Wg, Wt, Wp, bg, bt, bp, Ww, W_all, Ww16, b_all);
    k1_conv<<<dim3(32, 3, 8), 256, 0, stream>>>(x, W_all, b_all, OutT, Kmat, Vmat);
    k3_attn<<<512, 256, 0, stream>>>(OutT, Kmat, Vmat, Ww16, bw, wy);
    k4s_stats<<<256, 256, 0, stream>>>(wy, stats);
    k5_bnmax<<<2048, 256, 0, stream>>>(wy, x, stats, gamma, beta, outp);
}